// Round 1
// baseline (830.502 us; speedup 1.0000x reference)
//
#include <hip/hip_runtime.h>

// ---------------------------------------------------------------------------
// GAT (2-layer, PyG-style) on MI355X.
// Pipeline:
//   0. detect edge_index element width (int64 vs int32), normalize to int32
//   1. CSR by dst: histogram -> single-block scan -> fill (counting sort)
//   2. W1^T, W2^T -> bf16
//   3. GEMM1 (bf16 MFMA 32x32x16): xw1 = x @ W1          [N,256] fp32
//   4. alpha_src1/alpha_dst1 per (node,head)
//   5. pass1 L1: online softmax max+denom per (node,head)
//   6. pass2 L1: wave/node gather-aggregate + bias + ELU -> h (bf16)
//   7. GEMM2: xw2 = h @ W2                                [N,64] fp32
//   8. alpha2, pass1 L2, pass2 L2 (+log_softmax fused) -> out fp32
// Workspace use ~107 MB.
// ---------------------------------------------------------------------------

typedef __attribute__((ext_vector_type(8)))  __bf16          bf16x8;
typedef __attribute__((ext_vector_type(8)))  unsigned short  ushort8;
typedef __attribute__((ext_vector_type(16))) float           f32x16;

#define NEG_SLOPE 0.2f
#define EPS_GAT 1e-16f

static __device__ __forceinline__ float lrelu(float x) {
    return x > 0.0f ? x : NEG_SLOPE * x;
}
static __device__ __forceinline__ unsigned short f2bf(float f) {
    unsigned u = __float_as_uint(f);
    return (unsigned short)((u + 0x7fffu + ((u >> 16) & 1u)) >> 16);
}

// --------------------------- edge normalization ----------------------------
// If data is int64, the high word of every element is 0 (values < 2^31).
// If int32, odd words are random node ids in [0,N) -> ~E/N of them are 0,
// so "all odd words zero over E pairs" identifies int64 (P(err) ~ e^-16).
__global__ void k_flag(const unsigned* __restrict__ p, unsigned* sentinel, int E) {
    int i = blockIdx.x * 256 + threadIdx.x;
    unsigned w = 0;
    if (i < E) w = p[2 * i + 1];
    if (__any(w != 0)) {
        if ((threadIdx.x & 63) == 0) atomicOr(sentinel, 1u);
    }
}

__global__ void k_convert(const void* __restrict__ p, const unsigned* __restrict__ sentinel,
                          int* __restrict__ esrc, int* __restrict__ edst, int E) {
    int i = blockIdx.x * 256 + threadIdx.x;
    if (i >= 2 * E) return;
    bool is64 = (*sentinel == 0u);
    int v = is64 ? (int)((const long long*)p)[i] : ((const int*)p)[i];
    if (i < E) esrc[i] = v;
    else       edst[i - E] = v;
}

// ------------------------------- CSR build ---------------------------------
__global__ void k_hist(const int* __restrict__ edst, int* __restrict__ counts, int E) {
    int i = blockIdx.x * 256 + threadIdx.x;
    if (i < E) atomicAdd(&counts[edst[i]], 1);
}

__global__ __launch_bounds__(1024) void k_scan(const int* __restrict__ counts,
                                               int* __restrict__ row_ptr,
                                               int* __restrict__ cursor, int N) {
    __shared__ int sums[1024];
    int tid = threadIdx.x;
    int chunk = (N + 1023) >> 10;
    int begin = tid * chunk;
    int end   = begin + chunk; if (end > N) end = N;
    int s = 0;
    for (int i = begin; i < end; ++i) s += counts[i];
    sums[tid] = s;
    __syncthreads();
    for (int off = 1; off < 1024; off <<= 1) {
        int v = (tid >= off) ? sums[tid - off] : 0;
        __syncthreads();
        sums[tid] += v;
        __syncthreads();
    }
    int run = (tid > 0) ? sums[tid - 1] : 0;   // exclusive prefix of chunks
    for (int i = begin; i < end; ++i) {
        row_ptr[i] = run;
        cursor[i]  = run;
        run += counts[i];
    }
    if (tid == 0) row_ptr[N] = sums[1023];
}

__global__ void k_fill(const int* __restrict__ esrc, const int* __restrict__ edst,
                       int* __restrict__ cursor, int* __restrict__ sorted_src, int E) {
    int i = blockIdx.x * 256 + threadIdx.x;
    if (i >= E) return;
    int d = edst[i];
    int pos = atomicAdd(&cursor[d], 1);
    sorted_src[pos] = esrc[i];
}

// --------------------------- weight prep (bf16^T) --------------------------
__global__ void k_prep_w(const float* __restrict__ W1, const float* __restrict__ W2,
                         unsigned short* __restrict__ w1t, unsigned short* __restrict__ w2t) {
    int t = blockIdx.x * 256 + threadIdx.x;
    if (t < 512 * 256) {
        int k = t >> 8, m = t & 255;
        w1t[m * 512 + k] = f2bf(W1[t]);
    } else {
        int u = t - 512 * 256;
        if (u < 256 * 64) {
            int k = u >> 6, m = u & 63;
            w2t[m * 256 + k] = f2bf(W2[u]);
        }
    }
}

// ------------------------------- bf16 GEMM ---------------------------------
// C[N,BN] = A[N,K] @ B[K,BN], B supplied transposed+bf16 (Bt[BN][K]).
// 4 waves/block, each wave computes 64x64 via 2x2 of mfma_f32_32x32x16_bf16.
// A-frag: m=lane&31, k=(lane>>5)*8+j ; B-frag: n=lane&31, same k.
// C/D:    col=lane&31, row=(reg&3)+8*(reg>>2)+4*(lane>>5). (verified m74/m101)
template <int BM, int BN, bool AF32>
__global__ __launch_bounds__(256) void k_gemm(const void* __restrict__ Ain,
                                              const unsigned short* __restrict__ Bt,
                                              float* __restrict__ C, int Nrows, int K) {
    constexpr int LD = 40;                       // 32 + 8 pad, rows stay 16B-aligned
    __shared__ __align__(16) unsigned short As[BM * LD];
    __shared__ __align__(16) unsigned short Bs[BN * LD];
    const int tid = threadIdx.x;
    const int blockRow = blockIdx.x * BM;
    const int wave = tid >> 6, lane = tid & 63;
    constexpr int WR = BM / 64;                  // wave grid rows (WR*WC==4)
    const int wr = wave % WR, wc = wave / WR;
    const int m = lane & 31;
    const int ksel = (lane >> 5) * 8;

    f32x16 acc00{}, acc01{}, acc10{}, acc11{};

    for (int kt = 0; kt < K; kt += 32) {
        // ---- stage A tile [BM x 32] ----
        if constexpr (AF32) {
            const float* A = (const float*)Ain;
            for (int idx = tid; idx < BM * 4; idx += 256) {
                int r = idx >> 2, kc = (idx & 3) * 8;
                int grow = blockRow + r;
                float v[8];
                if (grow < Nrows) {
                    const float* ap = A + (size_t)grow * K + kt + kc;
                    float4 x0 = *(const float4*)ap;
                    float4 x1 = *(const float4*)(ap + 4);
                    v[0]=x0.x; v[1]=x0.y; v[2]=x0.z; v[3]=x0.w;
                    v[4]=x1.x; v[5]=x1.y; v[6]=x1.z; v[7]=x1.w;
                } else {
                    #pragma unroll
                    for (int t = 0; t < 8; ++t) v[t] = 0.0f;
                }
                ushort8 o;
                #pragma unroll
                for (int t = 0; t < 8; ++t) o[t] = f2bf(v[t]);
                *(ushort8*)&As[r * LD + kc] = o;
            }
        } else {
            const unsigned short* A = (const unsigned short*)Ain;
            for (int idx = tid; idx < BM * 4; idx += 256) {
                int r = idx >> 2, kc = (idx & 3) * 8;
                int grow = blockRow + r;
                ushort8 o{};
                if (grow < Nrows) o = *(const ushort8*)(A + (size_t)grow * K + kt + kc);
                *(ushort8*)&As[r * LD + kc] = o;
            }
        }
        // ---- stage B tile [BN x 32] ----
        for (int idx = tid; idx < BN * 4; idx += 256) {
            int r = idx >> 2, kc = (idx & 3) * 8;
            *(ushort8*)&Bs[r * LD + kc] = *(const ushort8*)(Bt + (size_t)r * K + kt + kc);
        }
        __syncthreads();

        #pragma unroll
        for (int kk = 0; kk < 32; kk += 16) {
            bf16x8 a0 = *(const bf16x8*)&As[(wr * 64 +      m) * LD + kk + ksel];
            bf16x8 a1 = *(const bf16x8*)&As[(wr * 64 + 32 + m) * LD + kk + ksel];
            bf16x8 b0 = *(const bf16x8*)&Bs[(wc * 64 +      m) * LD + kk + ksel];
            bf16x8 b1 = *(const bf16x8*)&Bs[(wc * 64 + 32 + m) * LD + kk + ksel];
            acc00 = __builtin_amdgcn_mfma_f32_32x32x16_bf16(a0, b0, acc00, 0, 0, 0);
            acc01 = __builtin_amdgcn_mfma_f32_32x32x16_bf16(a0, b1, acc01, 0, 0, 0);
            acc10 = __builtin_amdgcn_mfma_f32_32x32x16_bf16(a1, b0, acc10, 0, 0, 0);
            acc11 = __builtin_amdgcn_mfma_f32_32x32x16_bf16(a1, b1, acc11, 0, 0, 0);
        }
        __syncthreads();
    }

    const int dcol = wc * 64 + (lane & 31);
    const int dquad = 4 * (lane >> 5);
    auto store_tile = [&](const f32x16& a, int rt, int ct) {
        #pragma unroll
        for (int r = 0; r < 16; ++r) {
            int row = blockRow + wr * 64 + rt * 32 + (r & 3) + 8 * (r >> 2) + dquad;
            if (row < Nrows) C[(size_t)row * BN + dcol + ct * 32] = a[r];
        }
    };
    store_tile(acc00, 0, 0); store_tile(acc01, 0, 1);
    store_tile(acc10, 1, 0); store_tile(acc11, 1, 1);
}

// --------------------------- attention logits ------------------------------
// os[n*H+h] = sum_c xw[n, h*C+c] * a_s[h*C+c]  (same for od)
__global__ void k_alpha(const float* __restrict__ xw, const float* __restrict__ a_s,
                        const float* __restrict__ a_d, float* __restrict__ os,
                        float* __restrict__ od, int N, int H, int C) {
    int t = blockIdx.x * 256 + threadIdx.x;
    if (t >= N * H) return;
    int n = t / H, h = t - n * H;
    const float* row = xw + (size_t)n * H * C + h * C;
    float s = 0.f, d = 0.f;
    for (int c = 0; c < C; c += 4) {
        float4 v  = *(const float4*)(row + c);
        float4 av = *(const float4*)(a_s + h * C + c);
        float4 bv = *(const float4*)(a_d + h * C + c);
        s += v.x * av.x + v.y * av.y + v.z * av.z + v.w * av.w;
        d += v.x * bv.x + v.y * bv.y + v.z * bv.z + v.w * bv.w;
    }
    os[t] = s; od[t] = d;
}

// --------------------- pass 1: online softmax max+denom --------------------
__global__ void k_pass1(const float* __restrict__ asrc, const float* __restrict__ adst,
                        const int* __restrict__ rp, const int* __restrict__ sorted_src,
                        float* __restrict__ mo, float* __restrict__ so, int N, int H) {
    int t = blockIdx.x * 256 + threadIdx.x;
    if (t >= N * H) return;
    int n = t / H, h = t - n * H;
    float ad = adst[t];
    float m = lrelu(asrc[t] + ad);   // self-loop
    float s = 1.0f;
    int e1 = rp[n + 1];
    for (int e = rp[n]; e < e1; ++e) {
        int j = sorted_src[e];
        float ee = lrelu(asrc[j * H + h] + ad);
        if (ee <= m) {
            s += expf(ee - m);
        } else {
            s = s * expf(m - ee) + 1.0f;
            m = ee;
        }
    }
    mo[t] = m; so[t] = s;
}

// ------------------ pass 2 layer 1: aggregate + ELU -> bf16 ----------------
__global__ __launch_bounds__(256) void k_pass2_l1(
        const float* __restrict__ xw1, const float* __restrict__ asrc,
        const float* __restrict__ adst, const float* __restrict__ m1,
        const float* __restrict__ den1, const float* __restrict__ b1,
        const int* __restrict__ rp, const int* __restrict__ sorted_src,
        unsigned short* __restrict__ hbf, int N) {
    int wid = (blockIdx.x * 256 + threadIdx.x) >> 6;
    if (wid >= N) return;
    int lane = threadIdx.x & 63;
    int h = lane >> 3;          // 8 lanes per head
    int f0 = lane * 4;          // 4 features per lane, h == f0/32
    int ih = wid * 8 + h;
    float ad = adst[ih], mm = m1[ih];
    float inv = 1.0f / (den1[ih] + EPS_GAT);
    float ax = 0.f, ay = 0.f, az = 0.f, aw = 0.f;
    {   // self-loop
        float w = expf(lrelu(asrc[ih] + ad) - mm);
        float4 xv = *(const float4*)(xw1 + (size_t)wid * 256 + f0);
        ax += w * xv.x; ay += w * xv.y; az += w * xv.z; aw += w * xv.w;
    }
    int e1 = rp[wid + 1];
    for (int e = rp[wid]; e < e1; ++e) {
        int j = sorted_src[e];
        float w = expf(lrelu(asrc[j * 8 + h] + ad) - mm);
        float4 xv = *(const float4*)(xw1 + (size_t)j * 256 + f0);
        ax += w * xv.x; ay += w * xv.y; az += w * xv.z; aw += w * xv.w;
    }
    float v0 = ax * inv + b1[f0 + 0];
    float v1 = ay * inv + b1[f0 + 1];
    float v2 = az * inv + b1[f0 + 2];
    float v3 = aw * inv + b1[f0 + 3];
    v0 = v0 > 0.f ? v0 : expm1f(v0);
    v1 = v1 > 0.f ? v1 : expm1f(v1);
    v2 = v2 > 0.f ? v2 : expm1f(v2);
    v3 = v3 > 0.f ? v3 : expm1f(v3);
    ushort4 o;
    o.x = f2bf(v0); o.y = f2bf(v1); o.z = f2bf(v2); o.w = f2bf(v3);
    *(ushort4*)(hbf + (size_t)wid * 256 + f0) = o;
}

// --------- pass 2 layer 2: aggregate + bias + log_softmax -> out -----------
__global__ __launch_bounds__(256) void k_pass2_l2(
        const float* __restrict__ xw2, const float* __restrict__ asrc,
        const float* __restrict__ adst, const float* __restrict__ m2,
        const float* __restrict__ den2, const float* __restrict__ b2,
        const int* __restrict__ rp, const int* __restrict__ sorted_src,
        float* __restrict__ out, int N) {
    int wid = (blockIdx.x * 256 + threadIdx.x) >> 6;
    if (wid >= N) return;
    int lane = threadIdx.x & 63;    // lane == output class c
    float ad = adst[wid], mm = m2[wid];
    float inv = 1.0f / (den2[wid] + EPS_GAT);
    float acc = 0.f;
    {   // self-loop
        float w = expf(lrelu(asrc[wid] + ad) - mm);
        acc += w * xw2[(size_t)wid * 64 + lane];
    }
    int e1 = rp[wid + 1];
    for (int e = rp[wid]; e < e1; ++e) {
        int j = sorted_src[e];
        float w = expf(lrelu(asrc[j] + ad) - mm);
        acc += w * xw2[(size_t)j * 64 + lane];
    }
    float val = acc * inv + b2[lane];
    // wave-wide log_softmax over 64 classes
    float mx = val;
    #pragma unroll
    for (int off = 32; off > 0; off >>= 1) mx = fmaxf(mx, __shfl_xor(mx, off, 64));
    float sm = expf(val - mx);
    #pragma unroll
    for (int off = 32; off > 0; off >>= 1) sm += __shfl_xor(sm, off, 64);
    out[(size_t)wid * 64 + lane] = val - mx - logf(sm);
}

// ------------------------------- launcher ----------------------------------
static inline int cdiv(int a, int b) { return (a + b - 1) / b; }

extern "C" void kernel_launch(void* const* d_in, const int* in_sizes, int n_in,
                              void* d_out, int out_size, void* d_ws, size_t ws_size,
                              hipStream_t stream) {
    const float* x   = (const float*)d_in[0];
    const void*  eix = d_in[1];
    const float* W1  = (const float*)d_in[2];
    const float* as1 = (const float*)d_in[3];
    const float* ad1 = (const float*)d_in[4];
    const float* b1  = (const float*)d_in[5];
    const float* W2  = (const float*)d_in[6];
    const float* as2 = (const float*)d_in[7];
    const float* ad2 = (const float*)d_in[8];
    const float* b2  = (const float*)d_in[9];
    float* out = (float*)d_out;

    const int N = in_sizes[0] / 512;
    const int E = in_sizes[1] / 2;
    (void)n_in; (void)out_size; (void)ws_size;

    // workspace carve-up (256B aligned slots), total ~107 MB
    char* base = (char*)d_ws;
    size_t o = 0;
    auto alloc = [&](size_t bytes) -> char* {
        o = (o + 255) & ~(size_t)255;
        char* p = base + o;
        o += bytes;
        return p;
    };
    float*          xw1   = (float*)alloc((size_t)N * 256 * 4);
    unsigned short* hbf   = (unsigned short*)alloc((size_t)N * 256 * 2);
    float*          xw2   = (float*)alloc((size_t)N * 64 * 4);
    float*          asrc1 = (float*)alloc((size_t)N * 8 * 4);
    float*          adst1 = (float*)alloc((size_t)N * 8 * 4);
    float*          m1    = (float*)alloc((size_t)N * 8 * 4);
    float*          den1  = (float*)alloc((size_t)N * 8 * 4);
    float*          asrc2 = (float*)alloc((size_t)N * 4);
    float*          adst2 = (float*)alloc((size_t)N * 4);
    float*          m2    = (float*)alloc((size_t)N * 4);
    float*          den2  = (float*)alloc((size_t)N * 4);
    unsigned short* w1t   = (unsigned short*)alloc(512 * 256 * 2);
    unsigned short* w2t   = (unsigned short*)alloc(256 * 64 * 2);
    int*            counts= (int*)alloc((size_t)N * 4);
    int*            cursor= (int*)alloc((size_t)N * 4);
    int*            rowp  = (int*)alloc((size_t)(N + 1) * 4);
    int*            esrc  = (int*)alloc((size_t)E * 4);
    int*            edst  = (int*)alloc((size_t)E * 4);
    int*            ssrc  = (int*)alloc((size_t)E * 4);
    unsigned*       sent  = (unsigned*)alloc(256);

    hipMemsetAsync(sent, 0, 4, stream);
    hipMemsetAsync(counts, 0, (size_t)N * 4, stream);

    // edge normalization + CSR
    k_flag<<<cdiv(E, 256), 256, 0, stream>>>((const unsigned*)eix, sent, E);
    k_convert<<<cdiv(2 * E, 256), 256, 0, stream>>>(eix, sent, esrc, edst, E);
    k_hist<<<cdiv(E, 256), 256, 0, stream>>>(edst, counts, E);
    k_scan<<<1, 1024, 0, stream>>>(counts, rowp, cursor, N);
    k_fill<<<cdiv(E, 256), 256, 0, stream>>>(esrc, edst, cursor, ssrc, E);

    // weights -> bf16 transposed
    k_prep_w<<<cdiv(512 * 256 + 256 * 64, 256), 256, 0, stream>>>(W1, W2, w1t, w2t);

    // layer 1
    k_gemm<64, 256, true><<<cdiv(N, 64), 256, 0, stream>>>(x, w1t, xw1, N, 512);
    k_alpha<<<cdiv(N * 8, 256), 256, 0, stream>>>(xw1, as1, ad1, asrc1, adst1, N, 8, 32);
    k_pass1<<<cdiv(N * 8, 256), 256, 0, stream>>>(asrc1, adst1, rowp, ssrc, m1, den1, N, 8);
    k_pass2_l1<<<cdiv(N * 64, 256), 256, 0, stream>>>(xw1, asrc1, adst1, m1, den1, b1,
                                                      rowp, ssrc, hbf, N);
    // layer 2
    k_gemm<256, 64, false><<<cdiv(N, 256), 256, 0, stream>>>(hbf, w2t, xw2, N, 256);
    k_alpha<<<cdiv(N, 256), 256, 0, stream>>>(xw2, as2, ad2, asrc2, adst2, N, 1, 64);
    k_pass1<<<cdiv(N, 256), 256, 0, stream>>>(asrc2, adst2, rowp, ssrc, m2, den2, N, 1);
    k_pass2_l2<<<cdiv(N * 64, 256), 256, 0, stream>>>(xw2, asrc2, adst2, m2, den2, b2,
                                                      rowp, ssrc, out, N);
}

// Round 2
// 535.136 us; speedup vs baseline: 1.5519x; 1.5519x over previous
//
#include <hip/hip_runtime.h>

// ---------------------------------------------------------------------------
// GAT (2-layer, PyG-style) on MI355X.
// R2: k_flag -> 1-block sampler (kills 145us same-address atomic serialization)
//     hierarchical CSR scan, hist fused into convert,
//     pass1+pass2 fused (online softmax), xw1 stored bf16 (halves gather bytes)
// ---------------------------------------------------------------------------

typedef __attribute__((ext_vector_type(8)))  __bf16          bf16x8;
typedef __attribute__((ext_vector_type(8)))  unsigned short  ushort8;
typedef __attribute__((ext_vector_type(16))) float           f32x16;

#define NEG_SLOPE 0.2f
#define EPS_GAT 1e-16f

static __device__ __forceinline__ float lrelu(float x) {
    return x > 0.0f ? x : NEG_SLOPE * x;
}
static __device__ __forceinline__ unsigned short f2bf(float f) {
    unsigned u = __float_as_uint(f);
    return (unsigned short)((u + 0x7fffu + ((u >> 16) & 1u)) >> 16);
}
static __device__ __forceinline__ float bf2f(unsigned short v) {
    return __uint_as_float(((unsigned)v) << 16);
}

// --------------------------- edge normalization ----------------------------
// Sample 256 odd 32-bit words. int64 input => all are high words == 0.
// int32 input => words are random node ids, P(all 256 == 0) ~ (1/N)^256 ~ 0.
__global__ void k_flag(const unsigned* __restrict__ p, unsigned* sentinel, int E) {
    __shared__ int anynz;
    if (threadIdx.x == 0) anynz = 0;
    __syncthreads();
    int i = threadIdx.x;
    unsigned w = (i < E) ? p[2 * i + 1] : 0u;
    if (w != 0u) atomicOr(&anynz, 1);
    __syncthreads();
    if (threadIdx.x == 0 && anynz) *sentinel = 1u;   // 1 => int32 data
}

// convert + fused dst histogram
__global__ void k_convert(const void* __restrict__ p, const unsigned* __restrict__ sentinel,
                          int* __restrict__ esrc, int* __restrict__ edst,
                          int* __restrict__ counts, int E) {
    int i = blockIdx.x * 256 + threadIdx.x;
    if (i >= 2 * E) return;
    bool is64 = (*sentinel == 0u);
    int v = is64 ? (int)((const long long*)p)[i] : ((const int*)p)[i];
    if (i < E) {
        esrc[i] = v;
    } else {
        edst[i - E] = v;
        atomicAdd(&counts[v], 1);
    }
}

// ------------------------------- CSR build ---------------------------------
// hierarchical exclusive scan of counts[N] -> rowp[N+1], cursor[N]
__global__ void k_scan1(const int* __restrict__ counts, int* __restrict__ rowp,
                        int* __restrict__ bsum, int N) {
    __shared__ int s[256];
    int t = threadIdx.x, i = blockIdx.x * 256 + t;
    int v = (i < N) ? counts[i] : 0;
    s[t] = v;
    __syncthreads();
    for (int off = 1; off < 256; off <<= 1) {
        int u = (t >= off) ? s[t - off] : 0;
        __syncthreads();
        s[t] += u;
        __syncthreads();
    }
    if (i < N) rowp[i] = s[t] - v;          // exclusive within block
    if (t == 255) bsum[blockIdx.x] = s[255];
}

__global__ void k_scan2(const int* __restrict__ bsum, int* __restrict__ boff,
                        int* __restrict__ rowp_last, int NB) {
    __shared__ int s[256];
    int t = threadIdx.x;
    int v = (t < NB) ? bsum[t] : 0;
    s[t] = v;
    __syncthreads();
    for (int off = 1; off < 256; off <<= 1) {
        int u = (t >= off) ? s[t - off] : 0;
        __syncthreads();
        s[t] += u;
        __syncthreads();
    }
    if (t < NB) boff[t] = s[t] - v;
    if (t == 255) *rowp_last = s[255];      // == E
}

__global__ void k_scan3(int* __restrict__ rowp, int* __restrict__ cursor,
                        const int* __restrict__ boff, int N) {
    int i = blockIdx.x * 256 + threadIdx.x;
    if (i < N) {
        int r = rowp[i] + boff[blockIdx.x];
        rowp[i] = r;
        cursor[i] = r;
    }
}

__global__ void k_fill(const int* __restrict__ esrc, const int* __restrict__ edst,
                       int* __restrict__ cursor, int* __restrict__ sorted_src, int E) {
    int i = blockIdx.x * 256 + threadIdx.x;
    if (i >= E) return;
    int d = edst[i];
    int pos = atomicAdd(&cursor[d], 1);
    sorted_src[pos] = esrc[i];
}

// --------------------------- weight prep (bf16^T) --------------------------
__global__ void k_prep_w(const float* __restrict__ W1, const float* __restrict__ W2,
                         unsigned short* __restrict__ w1t, unsigned short* __restrict__ w2t) {
    int t = blockIdx.x * 256 + threadIdx.x;
    if (t < 512 * 256) {
        int k = t >> 8, m = t & 255;
        w1t[m * 512 + k] = f2bf(W1[t]);
    } else {
        int u = t - 512 * 256;
        if (u < 256 * 64) {
            int k = u >> 6, m = u & 63;
            w2t[m * 256 + k] = f2bf(W2[u]);
        }
    }
}

// ------------------------------- bf16 GEMM ---------------------------------
// C[N,BN] = A[N,K] @ B[K,BN]; Bt[BN][K] bf16. 4 waves/block, 64x64/wave via
// 2x2 mfma_f32_32x32x16_bf16. C/D: col=lane&31, row=(reg&3)+8*(reg>>2)+4*(lane>>5).
template <int BM, int BN, bool AF32, bool OUTBF>
__global__ __launch_bounds__(256) void k_gemm(const void* __restrict__ Ain,
                                              const unsigned short* __restrict__ Bt,
                                              void* __restrict__ Cout, int Nrows, int K) {
    constexpr int LD = 40;
    __shared__ __align__(16) unsigned short As[BM * LD];
    __shared__ __align__(16) unsigned short Bs[BN * LD];
    const int tid = threadIdx.x;
    const int blockRow = blockIdx.x * BM;
    const int wave = tid >> 6, lane = tid & 63;
    constexpr int WR = BM / 64;
    const int wr = wave % WR, wc = wave / WR;
    const int m = lane & 31;
    const int ksel = (lane >> 5) * 8;

    f32x16 acc00{}, acc01{}, acc10{}, acc11{};

    for (int kt = 0; kt < K; kt += 32) {
        if constexpr (AF32) {
            const float* A = (const float*)Ain;
            for (int idx = tid; idx < BM * 4; idx += 256) {
                int r = idx >> 2, kc = (idx & 3) * 8;
                int grow = blockRow + r;
                float v[8];
                if (grow < Nrows) {
                    const float* ap = A + (size_t)grow * K + kt + kc;
                    float4 x0 = *(const float4*)ap;
                    float4 x1 = *(const float4*)(ap + 4);
                    v[0]=x0.x; v[1]=x0.y; v[2]=x0.z; v[3]=x0.w;
                    v[4]=x1.x; v[5]=x1.y; v[6]=x1.z; v[7]=x1.w;
                } else {
                    #pragma unroll
                    for (int t = 0; t < 8; ++t) v[t] = 0.0f;
                }
                ushort8 o;
                #pragma unroll
                for (int t = 0; t < 8; ++t) o[t] = f2bf(v[t]);
                *(ushort8*)&As[r * LD + kc] = o;
            }
        } else {
            const unsigned short* A = (const unsigned short*)Ain;
            for (int idx = tid; idx < BM * 4; idx += 256) {
                int r = idx >> 2, kc = (idx & 3) * 8;
                int grow = blockRow + r;
                ushort8 o{};
                if (grow < Nrows) o = *(const ushort8*)(A + (size_t)grow * K + kt + kc);
                *(ushort8*)&As[r * LD + kc] = o;
            }
        }
        for (int idx = tid; idx < BN * 4; idx += 256) {
            int r = idx >> 2, kc = (idx & 3) * 8;
            *(ushort8*)&Bs[r * LD + kc] = *(const ushort8*)(Bt + (size_t)r * K + kt + kc);
        }
        __syncthreads();

        #pragma unroll
        for (int kk = 0; kk < 32; kk += 16) {
            bf16x8 a0 = *(const bf16x8*)&As[(wr * 64 +      m) * LD + kk + ksel];
            bf16x8 a1 = *(const bf16x8*)&As[(wr * 64 + 32 + m) * LD + kk + ksel];
            bf16x8 b0 = *(const bf16x8*)&Bs[(wc * 64 +      m) * LD + kk + ksel];
            bf16x8 b1 = *(const bf16x8*)&Bs[(wc * 64 + 32 + m) * LD + kk + ksel];
            acc00 = __builtin_amdgcn_mfma_f32_32x32x16_bf16(a0, b0, acc00, 0, 0, 0);
            acc01 = __builtin_amdgcn_mfma_f32_32x32x16_bf16(a0, b1, acc01, 0, 0, 0);
            acc10 = __builtin_amdgcn_mfma_f32_32x32x16_bf16(a1, b0, acc10, 0, 0, 0);
            acc11 = __builtin_amdgcn_mfma_f32_32x32x16_bf16(a1, b1, acc11, 0, 0, 0);
        }
        __syncthreads();
    }

    const int dcol = wc * 64 + (lane & 31);
    const int dquad = 4 * (lane >> 5);
    auto store_tile = [&](const f32x16& a, int rt, int ct) {
        #pragma unroll
        for (int r = 0; r < 16; ++r) {
            int row = blockRow + wr * 64 + rt * 32 + (r & 3) + 8 * (r >> 2) + dquad;
            if (row < Nrows) {
                size_t off = (size_t)row * BN + dcol + ct * 32;
                if constexpr (OUTBF) ((unsigned short*)Cout)[off] = f2bf(a[r]);
                else                 ((float*)Cout)[off] = a[r];
            }
        }
    };
    store_tile(acc00, 0, 0); store_tile(acc01, 0, 1);
    store_tile(acc10, 1, 0); store_tile(acc11, 1, 1);
}

// --------------------------- attention logits ------------------------------
// layer 1 (bf16 xw): os[n*H+h] = sum_c xw[n,h*C+c]*a_s[h*C+c]
__global__ void k_alpha_bf(const unsigned short* __restrict__ xw, const float* __restrict__ a_s,
                           const float* __restrict__ a_d, float* __restrict__ os,
                           float* __restrict__ od, int N, int H, int C) {
    int t = blockIdx.x * 256 + threadIdx.x;
    if (t >= N * H) return;
    int n = t / H, h = t - n * H;
    const unsigned short* row = xw + (size_t)n * H * C + h * C;
    float s = 0.f, d = 0.f;
    for (int c = 0; c < C; c += 8) {
        ushort8 v = *(const ushort8*)(row + c);
        #pragma unroll
        for (int q = 0; q < 8; ++q) {
            float f = bf2f(v[q]);
            s += f * a_s[h * C + c + q];
            d += f * a_d[h * C + c + q];
        }
    }
    os[t] = s; od[t] = d;
}

__global__ void k_alpha_f32(const float* __restrict__ xw, const float* __restrict__ a_s,
                            const float* __restrict__ a_d, float* __restrict__ os,
                            float* __restrict__ od, int N, int C) {
    int t = blockIdx.x * 256 + threadIdx.x;
    if (t >= N) return;
    const float* row = xw + (size_t)t * C;
    float s = 0.f, d = 0.f;
    for (int c = 0; c < C; c += 4) {
        float4 v  = *(const float4*)(row + c);
        float4 av = *(const float4*)(a_s + c);
        float4 bv = *(const float4*)(a_d + c);
        s += v.x * av.x + v.y * av.y + v.z * av.z + v.w * av.w;
        d += v.x * bv.x + v.y * bv.y + v.z * bv.z + v.w * bv.w;
    }
    os[t] = s; od[t] = d;
}

// ---------------- layer 1: fused online-softmax aggregation ----------------
// one wave per node; lane: h=lane>>3, features [lane*4, lane*4+4) of 256 (bf16)
__global__ __launch_bounds__(256) void k_agg_l1(
        const unsigned short* __restrict__ xw1, const float* __restrict__ asrc,
        const float* __restrict__ adst, const float* __restrict__ b1,
        const int* __restrict__ rp, const int* __restrict__ sorted_src,
        unsigned short* __restrict__ hbf, int N) {
    int wid = (blockIdx.x * 256 + threadIdx.x) >> 6;
    if (wid >= N) return;
    int lane = threadIdx.x & 63;
    int h = lane >> 3;
    int f0 = lane * 4;
    int ih = wid * 8 + h;
    float ad = adst[ih];
    // self-loop init (weight exp(0)=1)
    float m = lrelu(asrc[ih] + ad);
    float s = 1.0f;
    float ax, ay, az, aw;
    {
        ushort4 xv = *(const ushort4*)(xw1 + (size_t)wid * 256 + f0);
        ax = bf2f(xv.x); ay = bf2f(xv.y); az = bf2f(xv.z); aw = bf2f(xv.w);
    }
    int e1 = rp[wid + 1];
    for (int e = rp[wid]; e < e1; ++e) {
        int j = sorted_src[e];
        float ee = lrelu(asrc[j * 8 + h] + ad);
        float mn = fmaxf(m, ee);
        float w  = __expf(ee - mn);
        float sc = __expf(m - mn);
        ushort4 xv = *(const ushort4*)(xw1 + (size_t)j * 256 + f0);
        s  = s  * sc + w;
        ax = ax * sc + w * bf2f(xv.x);
        ay = ay * sc + w * bf2f(xv.y);
        az = az * sc + w * bf2f(xv.z);
        aw = aw * sc + w * bf2f(xv.w);
        m = mn;
    }
    float inv = 1.0f / (s + EPS_GAT);
    float v0 = ax * inv + b1[f0 + 0];
    float v1 = ay * inv + b1[f0 + 1];
    float v2 = az * inv + b1[f0 + 2];
    float v3 = aw * inv + b1[f0 + 3];
    v0 = v0 > 0.f ? v0 : expm1f(v0);
    v1 = v1 > 0.f ? v1 : expm1f(v1);
    v2 = v2 > 0.f ? v2 : expm1f(v2);
    v3 = v3 > 0.f ? v3 : expm1f(v3);
    ushort4 o;
    o.x = f2bf(v0); o.y = f2bf(v1); o.z = f2bf(v2); o.w = f2bf(v3);
    *(ushort4*)(hbf + (size_t)wid * 256 + f0) = o;
}

// -------- layer 2: fused online-softmax aggregation + log_softmax ----------
__global__ __launch_bounds__(256) void k_agg_l2(
        const float* __restrict__ xw2, const float* __restrict__ asrc,
        const float* __restrict__ adst, const float* __restrict__ b2,
        const int* __restrict__ rp, const int* __restrict__ sorted_src,
        float* __restrict__ out, int N) {
    int wid = (blockIdx.x * 256 + threadIdx.x) >> 6;
    if (wid >= N) return;
    int lane = threadIdx.x & 63;   // output class
    float ad = adst[wid];
    float m = lrelu(asrc[wid] + ad);
    float s = 1.0f;
    float acc = xw2[(size_t)wid * 64 + lane];
    int e1 = rp[wid + 1];
    for (int e = rp[wid]; e < e1; ++e) {
        int j = sorted_src[e];
        float ee = lrelu(asrc[j] + ad);
        float mn = fmaxf(m, ee);
        float w  = __expf(ee - mn);
        float sc = __expf(m - mn);
        s   = s   * sc + w;
        acc = acc * sc + w * xw2[(size_t)j * 64 + lane];
        m = mn;
    }
    float val = acc / (s + EPS_GAT) + b2[lane];
    float mx = val;
    #pragma unroll
    for (int off = 32; off > 0; off >>= 1) mx = fmaxf(mx, __shfl_xor(mx, off, 64));
    float sm = __expf(val - mx);
    #pragma unroll
    for (int off = 32; off > 0; off >>= 1) sm += __shfl_xor(sm, off, 64);
    out[(size_t)wid * 64 + lane] = val - mx - logf(sm);
}

// ------------------------------- launcher ----------------------------------
static inline int cdiv(int a, int b) { return (a + b - 1) / b; }

extern "C" void kernel_launch(void* const* d_in, const int* in_sizes, int n_in,
                              void* d_out, int out_size, void* d_ws, size_t ws_size,
                              hipStream_t stream) {
    const float* x   = (const float*)d_in[0];
    const void*  eix = d_in[1];
    const float* W1  = (const float*)d_in[2];
    const float* as1 = (const float*)d_in[3];
    const float* ad1 = (const float*)d_in[4];
    const float* b1  = (const float*)d_in[5];
    const float* W2  = (const float*)d_in[6];
    const float* as2 = (const float*)d_in[7];
    const float* ad2 = (const float*)d_in[8];
    const float* b2  = (const float*)d_in[9];
    float* out = (float*)d_out;

    const int N = in_sizes[0] / 512;
    const int E = in_sizes[1] / 2;
    const int NB = cdiv(N, 256);
    (void)n_in; (void)out_size; (void)ws_size;

    char* base = (char*)d_ws;
    size_t o = 0;
    auto alloc = [&](size_t bytes) -> char* {
        o = (o + 255) & ~(size_t)255;
        char* p = base + o;
        o += bytes;
        return p;
    };
    unsigned short* xw1b  = (unsigned short*)alloc((size_t)N * 256 * 2);
    unsigned short* hbf   = (unsigned short*)alloc((size_t)N * 256 * 2);
    float*          xw2   = (float*)alloc((size_t)N * 64 * 4);
    float*          asrc1 = (float*)alloc((size_t)N * 8 * 4);
    float*          adst1 = (float*)alloc((size_t)N * 8 * 4);
    float*          asrc2 = (float*)alloc((size_t)N * 4);
    float*          adst2 = (float*)alloc((size_t)N * 4);
    unsigned short* w1t   = (unsigned short*)alloc(512 * 256 * 2);
    unsigned short* w2t   = (unsigned short*)alloc(256 * 64 * 2);
    int*            counts= (int*)alloc((size_t)N * 4);
    int*            cursor= (int*)alloc((size_t)N * 4);
    int*            rowp  = (int*)alloc((size_t)(N + 1) * 4);
    int*            bsum  = (int*)alloc(256 * 4);
    int*            boff  = (int*)alloc(256 * 4);
    int*            esrc  = (int*)alloc((size_t)E * 4);
    int*            edst  = (int*)alloc((size_t)E * 4);
    int*            ssrc  = (int*)alloc((size_t)E * 4);
    unsigned*       sent  = (unsigned*)alloc(256);

    hipMemsetAsync(sent, 0, 4, stream);
    hipMemsetAsync(counts, 0, (size_t)N * 4, stream);

    // edge normalization + CSR
    k_flag<<<1, 256, 0, stream>>>((const unsigned*)eix, sent, E);
    k_convert<<<cdiv(2 * E, 256), 256, 0, stream>>>(eix, sent, esrc, edst, counts, E);
    k_scan1<<<NB, 256, 0, stream>>>(counts, rowp, bsum, N);
    k_scan2<<<1, 256, 0, stream>>>(bsum, boff, rowp + N, NB);
    k_scan3<<<NB, 256, 0, stream>>>(rowp, cursor, boff, N);
    k_fill<<<cdiv(E, 256), 256, 0, stream>>>(esrc, edst, cursor, ssrc, E);

    // weights -> bf16 transposed
    k_prep_w<<<cdiv(512 * 256 + 256 * 64, 256), 256, 0, stream>>>(W1, W2, w1t, w2t);

    // layer 1
    k_gemm<64, 256, true, true><<<cdiv(N, 64), 256, 0, stream>>>(x, w1t, xw1b, N, 512);
    k_alpha_bf<<<cdiv(N * 8, 256), 256, 0, stream>>>(xw1b, as1, ad1, asrc1, adst1, N, 8, 32);
    k_agg_l1<<<cdiv(N * 64, 256), 256, 0, stream>>>(xw1b, asrc1, adst1, b1, rowp, ssrc, hbf, N);

    // layer 2
    k_gemm<256, 64, false, false><<<cdiv(N, 256), 256, 0, stream>>>(hbf, w2t, xw2, N, 256);
    k_alpha_f32<<<cdiv(N, 256), 256, 0, stream>>>(xw2, as2, ad2, asrc2, adst2, N, 64);
    k_agg_l2<<<cdiv(N * 64, 256), 256, 0, stream>>>(xw2, asrc2, adst2, b2, rowp, ssrc, out, N);
}

// Round 3
// 516.385 us; speedup vs baseline: 1.6083x; 1.0363x over previous
//
#include <hip/hip_runtime.h>

// ---------------------------------------------------------------------------
// GAT (2-layer, PyG-style) on MI355X.
// R3: global-per-head-max softmax (lrelu monotone => lrelu(maxM+adst) bounds
//     all edge logits; rescale-free aggregation: 1 exp + 4 FMA per edge),
//     software-pipelined edge loops, xw2 stored bf16 (halves L2 gather),
//     GEMM1 128x256 tile / 512 threads.
// ---------------------------------------------------------------------------

typedef __attribute__((ext_vector_type(8)))  __bf16          bf16x8;
typedef __attribute__((ext_vector_type(8)))  unsigned short  ushort8;
typedef __attribute__((ext_vector_type(16))) float           f32x16;

#define NEG_SLOPE 0.2f
#define EPS_GAT 1e-16f

static __device__ __forceinline__ float lrelu(float x) {
    return x > 0.0f ? x : NEG_SLOPE * x;
}
static __device__ __forceinline__ unsigned short f2bf(float f) {
    unsigned u = __float_as_uint(f);
    return (unsigned short)((u + 0x7fffu + ((u >> 16) & 1u)) >> 16);
}
static __device__ __forceinline__ float bf2f(unsigned short v) {
    return __uint_as_float(((unsigned)v) << 16);
}

// --------------------------- edge normalization ----------------------------
__global__ void k_flag(const unsigned* __restrict__ p, unsigned* sentinel, int E) {
    __shared__ int anynz;
    if (threadIdx.x == 0) anynz = 0;
    __syncthreads();
    int i = threadIdx.x;
    unsigned w = (i < E) ? p[2 * i + 1] : 0u;
    if (w != 0u) atomicOr(&anynz, 1);
    __syncthreads();
    if (threadIdx.x == 0 && anynz) *sentinel = 1u;   // 1 => int32 data
}

__global__ void k_convert(const void* __restrict__ p, const unsigned* __restrict__ sentinel,
                          int* __restrict__ esrc, int* __restrict__ edst,
                          int* __restrict__ counts, int E) {
    int i = blockIdx.x * 256 + threadIdx.x;
    if (i >= 2 * E) return;
    bool is64 = (*sentinel == 0u);
    int v = is64 ? (int)((const long long*)p)[i] : ((const int*)p)[i];
    if (i < E) {
        esrc[i] = v;
    } else {
        edst[i - E] = v;
        atomicAdd(&counts[v], 1);
    }
}

// ------------------------------- CSR build ---------------------------------
__global__ void k_scan1(const int* __restrict__ counts, int* __restrict__ rowp,
                        int* __restrict__ bsum, int N) {
    __shared__ int s[256];
    int t = threadIdx.x, i = blockIdx.x * 256 + t;
    int v = (i < N) ? counts[i] : 0;
    s[t] = v;
    __syncthreads();
    for (int off = 1; off < 256; off <<= 1) {
        int u = (t >= off) ? s[t - off] : 0;
        __syncthreads();
        s[t] += u;
        __syncthreads();
    }
    if (i < N) rowp[i] = s[t] - v;
    if (t == 255) bsum[blockIdx.x] = s[255];
}

__global__ void k_scan2(const int* __restrict__ bsum, int* __restrict__ boff,
                        int* __restrict__ rowp_last, int NB) {
    __shared__ int s[256];
    int t = threadIdx.x;
    int v = (t < NB) ? bsum[t] : 0;
    s[t] = v;
    __syncthreads();
    for (int off = 1; off < 256; off <<= 1) {
        int u = (t >= off) ? s[t - off] : 0;
        __syncthreads();
        s[t] += u;
        __syncthreads();
    }
    if (t < NB) boff[t] = s[t] - v;
    if (t == 255) *rowp_last = s[255];
}

__global__ void k_scan3(int* __restrict__ rowp, int* __restrict__ cursor,
                        const int* __restrict__ boff, int N) {
    int i = blockIdx.x * 256 + threadIdx.x;
    if (i < N) {
        int r = rowp[i] + boff[blockIdx.x];
        rowp[i] = r;
        cursor[i] = r;
    }
}

__global__ void k_fill(const int* __restrict__ esrc, const int* __restrict__ edst,
                       int* __restrict__ cursor, int* __restrict__ sorted_src, int E) {
    int i = blockIdx.x * 256 + threadIdx.x;
    if (i >= E) return;
    int d = edst[i];
    int pos = atomicAdd(&cursor[d], 1);
    sorted_src[pos] = esrc[i];
}

// --------------------------- weight prep (bf16^T) --------------------------
__global__ void k_prep_w(const float* __restrict__ W1, const float* __restrict__ W2,
                         unsigned short* __restrict__ w1t, unsigned short* __restrict__ w2t) {
    int t = blockIdx.x * 256 + threadIdx.x;
    if (t < 512 * 256) {
        int k = t >> 8, m = t & 255;
        w1t[m * 512 + k] = f2bf(W1[t]);
    } else {
        int u = t - 512 * 256;
        if (u < 256 * 64) {
            int k = u >> 6, m = u & 63;
            w2t[m * 256 + k] = f2bf(W2[u]);
        }
    }
}

// ------------------------------- bf16 GEMM ---------------------------------
// C[N,BN] = A[N,K] @ B[K,BN]; Bt[BN][K] bf16. NT threads, 64x64/wave via
// 2x2 mfma_f32_32x32x16_bf16. C/D: col=lane&31, row=(reg&3)+8*(reg>>2)+4*(lane>>5).
template <int BM, int BN, int NT, bool AF32, bool OUTBF>
__global__ __launch_bounds__(NT) void k_gemm(const void* __restrict__ Ain,
                                             const unsigned short* __restrict__ Bt,
                                             void* __restrict__ Cout, int Nrows, int K) {
    constexpr int LD = 40;
    __shared__ __align__(16) unsigned short As[BM * LD];
    __shared__ __align__(16) unsigned short Bs[BN * LD];
    const int tid = threadIdx.x;
    const int blockRow = blockIdx.x * BM;
    const int wave = tid >> 6, lane = tid & 63;
    constexpr int WR = BM / 64;
    const int wr = wave % WR, wc = wave / WR;
    const int m = lane & 31;
    const int ksel = (lane >> 5) * 8;

    f32x16 acc00{}, acc01{}, acc10{}, acc11{};

    for (int kt = 0; kt < K; kt += 32) {
        if constexpr (AF32) {
            const float* A = (const float*)Ain;
            for (int idx = tid; idx < BM * 4; idx += NT) {
                int r = idx >> 2, kc = (idx & 3) * 8;
                int grow = blockRow + r;
                float v[8];
                if (grow < Nrows) {
                    const float* ap = A + (size_t)grow * K + kt + kc;
                    float4 x0 = *(const float4*)ap;
                    float4 x1 = *(const float4*)(ap + 4);
                    v[0]=x0.x; v[1]=x0.y; v[2]=x0.z; v[3]=x0.w;
                    v[4]=x1.x; v[5]=x1.y; v[6]=x1.z; v[7]=x1.w;
                } else {
                    #pragma unroll
                    for (int t = 0; t < 8; ++t) v[t] = 0.0f;
                }
                ushort8 o;
                #pragma unroll
                for (int t = 0; t < 8; ++t) o[t] = f2bf(v[t]);
                *(ushort8*)&As[r * LD + kc] = o;
            }
        } else {
            const unsigned short* A = (const unsigned short*)Ain;
            for (int idx = tid; idx < BM * 4; idx += NT) {
                int r = idx >> 2, kc = (idx & 3) * 8;
                int grow = blockRow + r;
                ushort8 o{};
                if (grow < Nrows) o = *(const ushort8*)(A + (size_t)grow * K + kt + kc);
                *(ushort8*)&As[r * LD + kc] = o;
            }
        }
        for (int idx = tid; idx < BN * 4; idx += NT) {
            int r = idx >> 2, kc = (idx & 3) * 8;
            *(ushort8*)&Bs[r * LD + kc] = *(const ushort8*)(Bt + (size_t)r * K + kt + kc);
        }
        __syncthreads();

        #pragma unroll
        for (int kk = 0; kk < 32; kk += 16) {
            bf16x8 a0 = *(const bf16x8*)&As[(wr * 64 +      m) * LD + kk + ksel];
            bf16x8 a1 = *(const bf16x8*)&As[(wr * 64 + 32 + m) * LD + kk + ksel];
            bf16x8 b0 = *(const bf16x8*)&Bs[(wc * 64 +      m) * LD + kk + ksel];
            bf16x8 b1 = *(const bf16x8*)&Bs[(wc * 64 + 32 + m) * LD + kk + ksel];
            acc00 = __builtin_amdgcn_mfma_f32_32x32x16_bf16(a0, b0, acc00, 0, 0, 0);
            acc01 = __builtin_amdgcn_mfma_f32_32x32x16_bf16(a0, b1, acc01, 0, 0, 0);
            acc10 = __builtin_amdgcn_mfma_f32_32x32x16_bf16(a1, b0, acc10, 0, 0, 0);
            acc11 = __builtin_amdgcn_mfma_f32_32x32x16_bf16(a1, b1, acc11, 0, 0, 0);
        }
        __syncthreads();
    }

    const int dcol = wc * 64 + (lane & 31);
    const int dquad = 4 * (lane >> 5);
    auto store_tile = [&](const f32x16& a, int rt, int ct) {
        #pragma unroll
        for (int r = 0; r < 16; ++r) {
            int row = blockRow + wr * 64 + rt * 32 + (r & 3) + 8 * (r >> 2) + dquad;
            if (row < Nrows) {
                size_t off = (size_t)row * BN + dcol + ct * 32;
                if constexpr (OUTBF) ((unsigned short*)Cout)[off] = f2bf(a[r]);
                else                 ((float*)Cout)[off] = a[r];
            }
        }
    };
    store_tile(acc00, 0, 0); store_tile(acc01, 0, 1);
    store_tile(acc10, 1, 0); store_tile(acc11, 1, 1);
}

// ------------------- attention logits + per-block head max -----------------
// t = n*H+h (256 % H == 0, so tid & (H-1) == h). xw is bf16 [N, H*C].
__global__ void k_alpha(const unsigned short* __restrict__ xw, const float* __restrict__ a_s,
                        const float* __restrict__ a_d, float* __restrict__ os,
                        float* __restrict__ od, float* __restrict__ pmax,
                        int NH, int H, int C) {
    __shared__ float red[256];
    int t = blockIdx.x * 256 + threadIdx.x;
    float s = -1e30f, d = 0.f;
    if (t < NH) {
        int n = t / H, h = t - n * H;
        const unsigned short* row = xw + (size_t)n * H * C + h * C;
        s = 0.f;
        for (int c = 0; c < C; c += 8) {
            ushort8 v = *(const ushort8*)(row + c);
            #pragma unroll
            for (int q = 0; q < 8; ++q) {
                float f = bf2f(v[q]);
                s += f * a_s[h * C + c + q];
                d += f * a_d[h * C + c + q];
            }
        }
        os[t] = s; od[t] = d;
    }
    red[threadIdx.x] = s;
    __syncthreads();
    for (int off = 128; off >= H; off >>= 1) {
        if (threadIdx.x < off) red[threadIdx.x] = fmaxf(red[threadIdx.x], red[threadIdx.x + off]);
        __syncthreads();
    }
    if ((int)threadIdx.x < H) pmax[blockIdx.x * H + threadIdx.x] = red[threadIdx.x];
}

// reduce per-block maxes -> M[h]
__global__ void k_maxred(const float* __restrict__ partial, int nB, int H,
                         float* __restrict__ M) {
    __shared__ float red[256];
    int t = threadIdx.x;
    int h = t & (H - 1);
    float m = -1e30f;
    for (int b = t / H; b < nB; b += 256 / H)
        m = fmaxf(m, partial[b * H + h]);
    red[t] = m;
    __syncthreads();
    for (int off = 128; off >= H; off >>= 1) {
        if (t < off) red[t] = fmaxf(red[t], red[t + off]);
        __syncthreads();
    }
    if (t < H) M[t] = red[t];
}

// ------------- layer 1: rescale-free softmax aggregation (bf16) ------------
// one wave/node; h=lane>>3, features [lane*4, lane*4+4) of 256
__global__ __launch_bounds__(256) void k_agg_l1(
        const unsigned short* __restrict__ xw1, const float* __restrict__ asrc,
        const float* __restrict__ adst, const float* __restrict__ Mh,
        const float* __restrict__ b1, const int* __restrict__ rp,
        const int* __restrict__ ssrc, unsigned short* __restrict__ hbf, int N) {
    int wid = (blockIdx.x * 256 + threadIdx.x) >> 6;
    if (wid >= N) return;
    int lane = threadIdx.x & 63;
    int h = lane >> 3;
    int f0 = lane * 4;
    int ih = wid * 8 + h;
    float ad = adst[ih];
    float m = lrelu(Mh[h] + ad);         // >= all edge logits (lrelu monotone)
    float s, ax, ay, az, aw;
    {   // self loop
        float w = __expf(lrelu(asrc[ih] + ad) - m);
        ushort4 xv = *(const ushort4*)(xw1 + (size_t)wid * 256 + f0);
        s = w;
        ax = w * bf2f(xv.x); ay = w * bf2f(xv.y);
        az = w * bf2f(xv.z); aw = w * bf2f(xv.w);
    }
    int e0 = rp[wid], e1 = rp[wid + 1];
    if (e0 < e1) {
        int j = ssrc[e0];
        float as_c = asrc[j * 8 + h];
        ushort4 xv_c = *(const ushort4*)(xw1 + (size_t)j * 256 + f0);
        for (int e = e0 + 1;; ++e) {
            bool more = e < e1;
            float as_n; ushort4 xv_n;
            if (more) {                  // prefetch next edge (wave-uniform)
                int jn = ssrc[e];
                as_n = asrc[jn * 8 + h];
                xv_n = *(const ushort4*)(xw1 + (size_t)jn * 256 + f0);
            }
            float w = __expf(lrelu(as_c + ad) - m);
            s += w;
            ax += w * bf2f(xv_c.x); ay += w * bf2f(xv_c.y);
            az += w * bf2f(xv_c.z); aw += w * bf2f(xv_c.w);
            if (!more) break;
            as_c = as_n; xv_c = xv_n;
        }
    }
    float inv = 1.0f / (s + EPS_GAT);
    float v0 = ax * inv + b1[f0 + 0];
    float v1 = ay * inv + b1[f0 + 1];
    float v2 = az * inv + b1[f0 + 2];
    float v3 = aw * inv + b1[f0 + 3];
    v0 = v0 > 0.f ? v0 : expm1f(v0);
    v1 = v1 > 0.f ? v1 : expm1f(v1);
    v2 = v2 > 0.f ? v2 : expm1f(v2);
    v3 = v3 > 0.f ? v3 : expm1f(v3);
    ushort4 o;
    o.x = f2bf(v0); o.y = f2bf(v1); o.z = f2bf(v2); o.w = f2bf(v3);
    *(ushort4*)(hbf + (size_t)wid * 256 + f0) = o;
}

// ------ layer 2: rescale-free aggregation (bf16 xw2) + log_softmax ---------
__global__ __launch_bounds__(256) void k_agg_l2(
        const unsigned short* __restrict__ xw2, const float* __restrict__ asrc,
        const float* __restrict__ adst, const float* __restrict__ Mh,
        const float* __restrict__ b2, const int* __restrict__ rp,
        const int* __restrict__ ssrc, float* __restrict__ out, int N) {
    int wid = (blockIdx.x * 256 + threadIdx.x) >> 6;
    if (wid >= N) return;
    int lane = threadIdx.x & 63;   // output class
    float ad = adst[wid];
    float m = lrelu(Mh[0] + ad);
    float s, acc;
    {
        float w = __expf(lrelu(asrc[wid] + ad) - m);
        s = w;
        acc = w * bf2f(xw2[(size_t)wid * 64 + lane]);
    }
    int e0 = rp[wid], e1 = rp[wid + 1];
    if (e0 < e1) {
        int j = ssrc[e0];
        float as_c = asrc[j];
        unsigned short xv_c = xw2[(size_t)j * 64 + lane];
        for (int e = e0 + 1;; ++e) {
            bool more = e < e1;
            float as_n; unsigned short xv_n;
            if (more) {
                int jn = ssrc[e];
                as_n = asrc[jn];
                xv_n = xw2[(size_t)jn * 64 + lane];
            }
            float w = __expf(lrelu(as_c + ad) - m);
            s += w;
            acc += w * bf2f(xv_c);
            if (!more) break;
            as_c = as_n; xv_c = xv_n;
        }
    }
    float val = acc / (s + EPS_GAT) + b2[lane];
    float mx = val;
    #pragma unroll
    for (int off = 32; off > 0; off >>= 1) mx = fmaxf(mx, __shfl_xor(mx, off, 64));
    float sm = __expf(val - mx);
    #pragma unroll
    for (int off = 32; off > 0; off >>= 1) sm += __shfl_xor(sm, off, 64);
    out[(size_t)wid * 64 + lane] = val - mx - logf(sm);
}

// ------------------------------- launcher ----------------------------------
static inline int cdiv(int a, int b) { return (a + b - 1) / b; }

extern "C" void kernel_launch(void* const* d_in, const int* in_sizes, int n_in,
                              void* d_out, int out_size, void* d_ws, size_t ws_size,
                              hipStream_t stream) {
    const float* x   = (const float*)d_in[0];
    const void*  eix = d_in[1];
    const float* W1  = (const float*)d_in[2];
    const float* as1 = (const float*)d_in[3];
    const float* ad1 = (const float*)d_in[4];
    const float* b1  = (const float*)d_in[5];
    const float* W2  = (const float*)d_in[6];
    const float* as2 = (const float*)d_in[7];
    const float* ad2 = (const float*)d_in[8];
    const float* b2  = (const float*)d_in[9];
    float* out = (float*)d_out;

    const int N = in_sizes[0] / 512;
    const int E = in_sizes[1] / 2;
    const int NB = cdiv(N, 256);
    const int NB1 = cdiv(N * 8, 256);   // alpha1 blocks
    const int NB2 = cdiv(N, 256);       // alpha2 blocks
    (void)n_in; (void)out_size; (void)ws_size;

    char* base = (char*)d_ws;
    size_t o = 0;
    auto alloc = [&](size_t bytes) -> char* {
        o = (o + 255) & ~(size_t)255;
        char* p = base + o;
        o += bytes;
        return p;
    };
    unsigned short* xw1b  = (unsigned short*)alloc((size_t)N * 256 * 2);
    unsigned short* hbf   = (unsigned short*)alloc((size_t)N * 256 * 2);
    unsigned short* xw2b  = (unsigned short*)alloc((size_t)N * 64 * 2);
    float*          asrc1 = (float*)alloc((size_t)N * 8 * 4);
    float*          adst1 = (float*)alloc((size_t)N * 8 * 4);
    float*          asrc2 = (float*)alloc((size_t)N * 4);
    float*          adst2 = (float*)alloc((size_t)N * 4);
    float*          pmax1 = (float*)alloc((size_t)NB1 * 8 * 4);
    float*          pmax2 = (float*)alloc((size_t)NB2 * 4);
    float*          M1    = (float*)alloc(8 * 4);
    float*          M2    = (float*)alloc(4);
    unsigned short* w1t   = (unsigned short*)alloc(512 * 256 * 2);
    unsigned short* w2t   = (unsigned short*)alloc(256 * 64 * 2);
    int*            counts= (int*)alloc((size_t)N * 4);
    int*            cursor= (int*)alloc((size_t)N * 4);
    int*            rowp  = (int*)alloc((size_t)(N + 1) * 4);
    int*            bsum  = (int*)alloc(256 * 4);
    int*            boff  = (int*)alloc(256 * 4);
    int*            esrc  = (int*)alloc((size_t)E * 4);
    int*            edst  = (int*)alloc((size_t)E * 4);
    int*            ssrc  = (int*)alloc((size_t)E * 4);
    unsigned*       sent  = (unsigned*)alloc(256);

    hipMemsetAsync(sent, 0, 4, stream);
    hipMemsetAsync(counts, 0, (size_t)N * 4, stream);

    // edge normalization + CSR
    k_flag<<<1, 256, 0, stream>>>((const unsigned*)eix, sent, E);
    k_convert<<<cdiv(2 * E, 256), 256, 0, stream>>>(eix, sent, esrc, edst, counts, E);
    k_scan1<<<NB, 256, 0, stream>>>(counts, rowp, bsum, N);
    k_scan2<<<1, 256, 0, stream>>>(bsum, boff, rowp + N, NB);
    k_scan3<<<NB, 256, 0, stream>>>(rowp, cursor, boff, N);
    k_fill<<<cdiv(E, 256), 256, 0, stream>>>(esrc, edst, cursor, ssrc, E);

    // weights -> bf16 transposed
    k_prep_w<<<cdiv(512 * 256 + 256 * 64, 256), 256, 0, stream>>>(W1, W2, w1t, w2t);

    // layer 1
    k_gemm<128, 256, 512, true, true><<<cdiv(N, 128), 512, 0, stream>>>(x, w1t, xw1b, N, 512);
    k_alpha<<<NB1, 256, 0, stream>>>(xw1b, as1, ad1, asrc1, adst1, pmax1, N * 8, 8, 32);
    k_maxred<<<1, 256, 0, stream>>>(pmax1, NB1, 8, M1);
    k_agg_l1<<<cdiv(N * 64, 256), 256, 0, stream>>>(xw1b, asrc1, adst1, M1, b1,
                                                    rowp, ssrc, hbf, N);
    // layer 2
    k_gemm<256, 64, 256, false, true><<<cdiv(N, 256), 256, 0, stream>>>(hbf, w2t, xw2b, N, 256);
    k_alpha<<<NB2, 256, 0, stream>>>(xw2b, as2, ad2, asrc2, adst2, pmax2, N, 1, 64);
    k_maxred<<<1, 256, 0, stream>>>(pmax2, NB2, 1, M2);
    k_agg_l2<<<cdiv(N * 64, 256), 256, 0, stream>>>(xw2b, asrc2, adst2, M2, b2,
                                                    rowp, ssrc, out, N);
}

// Round 4
// 449.051 us; speedup vs baseline: 1.8495x; 1.1499x over previous
//
#include <hip/hip_runtime.h>

// ---------------------------------------------------------------------------
// GAT (2-layer, PyG-style) on MI355X.
// R4: multi-edge-per-wave aggregation (l1: 2 edges x 32 lanes x 16B,
//     l2: 4 edges x 16 lanes x 8B) -> 2-4x MLP, ~2x fewer per-edge VALU ops.
//     Global-per-head-max softmax (rescale-free). xw1/xw2 bf16.
// ---------------------------------------------------------------------------

typedef __attribute__((ext_vector_type(8)))  __bf16          bf16x8;
typedef __attribute__((ext_vector_type(8)))  unsigned short  ushort8;
typedef __attribute__((ext_vector_type(16))) float           f32x16;

#define NEG_SLOPE 0.2f
#define EPS_GAT 1e-16f

static __device__ __forceinline__ float lrelu(float x) {
    return x > 0.0f ? x : NEG_SLOPE * x;
}
static __device__ __forceinline__ unsigned short f2bf(float f) {
    unsigned u = __float_as_uint(f);
    return (unsigned short)((u + 0x7fffu + ((u >> 16) & 1u)) >> 16);
}
static __device__ __forceinline__ float bf2f(unsigned short v) {
    return __uint_as_float(((unsigned)v) << 16);
}

// --------------------------- edge normalization ----------------------------
__global__ void k_flag(const unsigned* __restrict__ p, unsigned* sentinel, int E) {
    __shared__ int anynz;
    if (threadIdx.x == 0) anynz = 0;
    __syncthreads();
    int i = threadIdx.x;
    unsigned w = (i < E) ? p[2 * i + 1] : 0u;
    if (w != 0u) atomicOr(&anynz, 1);
    __syncthreads();
    if (threadIdx.x == 0 && anynz) *sentinel = 1u;   // 1 => int32 data
}

__global__ void k_convert(const void* __restrict__ p, const unsigned* __restrict__ sentinel,
                          int* __restrict__ esrc, int* __restrict__ edst,
                          int* __restrict__ counts, int E) {
    int i = blockIdx.x * 256 + threadIdx.x;
    if (i >= 2 * E) return;
    bool is64 = (*sentinel == 0u);
    int v = is64 ? (int)((const long long*)p)[i] : ((const int*)p)[i];
    if (i < E) {
        esrc[i] = v;
    } else {
        edst[i - E] = v;
        atomicAdd(&counts[v], 1);
    }
}

// ------------------------------- CSR build ---------------------------------
__global__ void k_scan1(const int* __restrict__ counts, int* __restrict__ rowp,
                        int* __restrict__ bsum, int N) {
    __shared__ int s[256];
    int t = threadIdx.x, i = blockIdx.x * 256 + t;
    int v = (i < N) ? counts[i] : 0;
    s[t] = v;
    __syncthreads();
    for (int off = 1; off < 256; off <<= 1) {
        int u = (t >= off) ? s[t - off] : 0;
        __syncthreads();
        s[t] += u;
        __syncthreads();
    }
    if (i < N) rowp[i] = s[t] - v;
    if (t == 255) bsum[blockIdx.x] = s[255];
}

__global__ void k_scan2(const int* __restrict__ bsum, int* __restrict__ boff,
                        int* __restrict__ rowp_last, int NB) {
    __shared__ int s[256];
    int t = threadIdx.x;
    int v = (t < NB) ? bsum[t] : 0;
    s[t] = v;
    __syncthreads();
    for (int off = 1; off < 256; off <<= 1) {
        int u = (t >= off) ? s[t - off] : 0;
        __syncthreads();
        s[t] += u;
        __syncthreads();
    }
    if (t < NB) boff[t] = s[t] - v;
    if (t == 255) *rowp_last = s[255];
}

__global__ void k_scan3(int* __restrict__ rowp, int* __restrict__ cursor,
                        const int* __restrict__ boff, int N) {
    int i = blockIdx.x * 256 + threadIdx.x;
    if (i < N) {
        int r = rowp[i] + boff[blockIdx.x];
        rowp[i] = r;
        cursor[i] = r;
    }
}

__global__ void k_fill(const int* __restrict__ esrc, const int* __restrict__ edst,
                       int* __restrict__ cursor, int* __restrict__ sorted_src, int E) {
    int i = blockIdx.x * 256 + threadIdx.x;
    if (i >= E) return;
    int d = edst[i];
    int pos = atomicAdd(&cursor[d], 1);
    sorted_src[pos] = esrc[i];
}

// --------------------------- weight prep (bf16^T) --------------------------
__global__ void k_prep_w(const float* __restrict__ W1, const float* __restrict__ W2,
                         unsigned short* __restrict__ w1t, unsigned short* __restrict__ w2t) {
    int t = blockIdx.x * 256 + threadIdx.x;
    if (t < 512 * 256) {
        int k = t >> 8, m = t & 255;
        w1t[m * 512 + k] = f2bf(W1[t]);
    } else {
        int u = t - 512 * 256;
        if (u < 256 * 64) {
            int k = u >> 6, m = u & 63;
            w2t[m * 256 + k] = f2bf(W2[u]);
        }
    }
}

// ------------------------------- bf16 GEMM ---------------------------------
template <int BM, int BN, int NT, bool AF32, bool OUTBF>
__global__ __launch_bounds__(NT) void k_gemm(const void* __restrict__ Ain,
                                             const unsigned short* __restrict__ Bt,
                                             void* __restrict__ Cout, int Nrows, int K) {
    constexpr int LD = 40;
    __shared__ __align__(16) unsigned short As[BM * LD];
    __shared__ __align__(16) unsigned short Bs[BN * LD];
    const int tid = threadIdx.x;
    const int blockRow = blockIdx.x * BM;
    const int wave = tid >> 6, lane = tid & 63;
    constexpr int WR = BM / 64;
    const int wr = wave % WR, wc = wave / WR;
    const int m = lane & 31;
    const int ksel = (lane >> 5) * 8;

    f32x16 acc00{}, acc01{}, acc10{}, acc11{};

    for (int kt = 0; kt < K; kt += 32) {
        if constexpr (AF32) {
            const float* A = (const float*)Ain;
            for (int idx = tid; idx < BM * 4; idx += NT) {
                int r = idx >> 2, kc = (idx & 3) * 8;
                int grow = blockRow + r;
                float v[8];
                if (grow < Nrows) {
                    const float* ap = A + (size_t)grow * K + kt + kc;
                    float4 x0 = *(const float4*)ap;
                    float4 x1 = *(const float4*)(ap + 4);
                    v[0]=x0.x; v[1]=x0.y; v[2]=x0.z; v[3]=x0.w;
                    v[4]=x1.x; v[5]=x1.y; v[6]=x1.z; v[7]=x1.w;
                } else {
                    #pragma unroll
                    for (int t = 0; t < 8; ++t) v[t] = 0.0f;
                }
                ushort8 o;
                #pragma unroll
                for (int t = 0; t < 8; ++t) o[t] = f2bf(v[t]);
                *(ushort8*)&As[r * LD + kc] = o;
            }
        } else {
            const unsigned short* A = (const unsigned short*)Ain;
            for (int idx = tid; idx < BM * 4; idx += NT) {
                int r = idx >> 2, kc = (idx & 3) * 8;
                int grow = blockRow + r;
                ushort8 o{};
                if (grow < Nrows) o = *(const ushort8*)(A + (size_t)grow * K + kt + kc);
                *(ushort8*)&As[r * LD + kc] = o;
            }
        }
        for (int idx = tid; idx < BN * 4; idx += NT) {
            int r = idx >> 2, kc = (idx & 3) * 8;
            *(ushort8*)&Bs[r * LD + kc] = *(const ushort8*)(Bt + (size_t)r * K + kt + kc);
        }
        __syncthreads();

        #pragma unroll
        for (int kk = 0; kk < 32; kk += 16) {
            bf16x8 a0 = *(const bf16x8*)&As[(wr * 64 +      m) * LD + kk + ksel];
            bf16x8 a1 = *(const bf16x8*)&As[(wr * 64 + 32 + m) * LD + kk + ksel];
            bf16x8 b0 = *(const bf16x8*)&Bs[(wc * 64 +      m) * LD + kk + ksel];
            bf16x8 b1 = *(const bf16x8*)&Bs[(wc * 64 + 32 + m) * LD + kk + ksel];
            acc00 = __builtin_amdgcn_mfma_f32_32x32x16_bf16(a0, b0, acc00, 0, 0, 0);
            acc01 = __builtin_amdgcn_mfma_f32_32x32x16_bf16(a0, b1, acc01, 0, 0, 0);
            acc10 = __builtin_amdgcn_mfma_f32_32x32x16_bf16(a1, b0, acc10, 0, 0, 0);
            acc11 = __builtin_amdgcn_mfma_f32_32x32x16_bf16(a1, b1, acc11, 0, 0, 0);
        }
        __syncthreads();
    }

    const int dcol = wc * 64 + (lane & 31);
    const int dquad = 4 * (lane >> 5);
    auto store_tile = [&](const f32x16& a, int rt, int ct) {
        #pragma unroll
        for (int r = 0; r < 16; ++r) {
            int row = blockRow + wr * 64 + rt * 32 + (r & 3) + 8 * (r >> 2) + dquad;
            if (row < Nrows) {
                size_t off = (size_t)row * BN + dcol + ct * 32;
                if constexpr (OUTBF) ((unsigned short*)Cout)[off] = f2bf(a[r]);
                else                 ((float*)Cout)[off] = a[r];
            }
        }
    };
    store_tile(acc00, 0, 0); store_tile(acc01, 0, 1);
    store_tile(acc10, 1, 0); store_tile(acc11, 1, 1);
}

// ------------------- attention logits + per-block head max -----------------
__global__ void k_alpha(const unsigned short* __restrict__ xw, const float* __restrict__ a_s,
                        const float* __restrict__ a_d, float* __restrict__ os,
                        float* __restrict__ od, float* __restrict__ pmax,
                        int NH, int H, int C) {
    __shared__ float red[256];
    int t = blockIdx.x * 256 + threadIdx.x;
    float s = -1e30f, d = 0.f;
    if (t < NH) {
        int n = t / H, h = t - n * H;
        const unsigned short* row = xw + (size_t)n * H * C + h * C;
        s = 0.f;
        for (int c = 0; c < C; c += 8) {
            ushort8 v = *(const ushort8*)(row + c);
            #pragma unroll
            for (int q = 0; q < 8; ++q) {
                float f = bf2f(v[q]);
                s += f * a_s[h * C + c + q];
                d += f * a_d[h * C + c + q];
            }
        }
        os[t] = s; od[t] = d;
    }
    red[threadIdx.x] = s;
    __syncthreads();
    for (int off = 128; off >= H; off >>= 1) {
        if (threadIdx.x < off) red[threadIdx.x] = fmaxf(red[threadIdx.x], red[threadIdx.x + off]);
        __syncthreads();
    }
    if ((int)threadIdx.x < H) pmax[blockIdx.x * H + threadIdx.x] = red[threadIdx.x];
}

__global__ void k_maxred(const float* __restrict__ partial, int nB, int H,
                         float* __restrict__ M) {
    __shared__ float red[256];
    int t = threadIdx.x;
    int h = t & (H - 1);
    float m = -1e30f;
    for (int b = t / H; b < nB; b += 256 / H)
        m = fmaxf(m, partial[b * H + h]);
    red[t] = m;
    __syncthreads();
    for (int off = 128; off >= H; off >>= 1) {
        if (t < off) red[t] = fmaxf(red[t], red[t + off]);
        __syncthreads();
    }
    if (t < H) M[t] = red[t];
}

// ------------- layer 1: 2-edges-per-wave rescale-free aggregation ----------
// half = lane>>5 picks edge of pair; q = lane&31 holds features [q*8, q*8+8)
__global__ __launch_bounds__(256) void k_agg_l1(
        const unsigned short* __restrict__ xw1, const float* __restrict__ asrc,
        const float* __restrict__ adst, const float* __restrict__ Mh,
        const float* __restrict__ b1, const int* __restrict__ rp,
        const int* __restrict__ ssrc, unsigned short* __restrict__ hbf, int N) {
    int wid = (blockIdx.x * 256 + threadIdx.x) >> 6;
    if (wid >= N) return;
    int lane = threadIdx.x & 63;
    int half = lane >> 5;
    int q    = lane & 31;
    int f0   = q * 8;
    int h    = q >> 2;
    int ih   = wid * 8 + h;
    float ad = adst[ih];
    float m  = lrelu(Mh[h] + ad);        // >= all edge logits (lrelu monotone)
    float acc[8];
    float s;
    {   // self loop counted on half 0 only
        float w = (half == 0) ? __expf(lrelu(asrc[ih] + ad) - m) : 0.0f;
        ushort8 xv = *(const ushort8*)(xw1 + (size_t)wid * 256 + f0);
        s = w;
        #pragma unroll
        for (int i = 0; i < 8; ++i) acc[i] = w * bf2f(xv[i]);
    }
    int e0 = rp[wid], e1 = rp[wid + 1];
    if (e0 < e1) {
        int ei = e0 + half;
        bool v_c = ei < e1;
        int j_c = ssrc[v_c ? ei : e1 - 1];
        float as_c = asrc[j_c * 8 + h];
        ushort8 xv_c = *(const ushort8*)(xw1 + (size_t)j_c * 256 + f0);
        for (int e = e0 + 2;; e += 2) {
            bool more = e < e1;
            bool v_n = false;
            float as_n;
            ushort8 xv_n;
            if (more) {                  // prefetch next pair
                int en = e + half;
                v_n = en < e1;
                int j_n = ssrc[v_n ? en : e1 - 1];
                as_n = asrc[j_n * 8 + h];
                xv_n = *(const ushort8*)(xw1 + (size_t)j_n * 256 + f0);
            }
            float w = v_c ? __expf(lrelu(as_c + ad) - m) : 0.0f;
            s += w;
            #pragma unroll
            for (int i = 0; i < 8; ++i) acc[i] += w * bf2f(xv_c[i]);
            if (!more) break;
            v_c = v_n; as_c = as_n; xv_c = xv_n;
        }
    }
    // combine halves
    s += __shfl_xor(s, 32, 64);
    #pragma unroll
    for (int i = 0; i < 8; ++i) acc[i] += __shfl_xor(acc[i], 32, 64);
    float inv = 1.0f / (s + EPS_GAT);
    // halves write disjoint 4-feature slices of [f0, f0+8)
    int fw = f0 + half * 4;
    ushort4 o;
    #pragma unroll
    for (int i = 0; i < 4; ++i) {
        float v = acc[half * 4 + i] * inv + b1[fw + i];
        v = v > 0.f ? v : expm1f(v);
        ((unsigned short*)&o)[i] = f2bf(v);
    }
    *(ushort4*)(hbf + (size_t)wid * 256 + fw) = o;
}

// ---- layer 2: 4-edges-per-wave aggregation + fused log_softmax ------------
// g = lane>>4 picks edge of quad; q = lane&15 holds classes [q*4, q*4+4)
__global__ __launch_bounds__(256) void k_agg_l2(
        const unsigned short* __restrict__ xw2, const float* __restrict__ asrc,
        const float* __restrict__ adst, const float* __restrict__ Mh,
        const float* __restrict__ b2, const int* __restrict__ rp,
        const int* __restrict__ ssrc, float* __restrict__ out, int N) {
    int wid = (blockIdx.x * 256 + threadIdx.x) >> 6;
    if (wid >= N) return;
    int lane = threadIdx.x & 63;
    int g  = lane >> 4;
    int q  = lane & 15;
    int f0 = q * 4;
    float ad = adst[wid];
    float m = lrelu(Mh[0] + ad);
    float acc[4];
    float s;
    {   // self loop counted on group 0 only
        float w = (g == 0) ? __expf(lrelu(asrc[wid] + ad) - m) : 0.0f;
        ushort4 xv = *(const ushort4*)(xw2 + (size_t)wid * 64 + f0);
        s = w;
        acc[0] = w * bf2f(xv.x); acc[1] = w * bf2f(xv.y);
        acc[2] = w * bf2f(xv.z); acc[3] = w * bf2f(xv.w);
    }
    int e0 = rp[wid], e1 = rp[wid + 1];
    if (e0 < e1) {
        int ei = e0 + g;
        bool v_c = ei < e1;
        int j_c = ssrc[v_c ? ei : e1 - 1];
        float as_c = asrc[j_c];
        ushort4 xv_c = *(const ushort4*)(xw2 + (size_t)j_c * 64 + f0);
        for (int e = e0 + 4;; e += 4) {
            bool more = e < e1;
            bool v_n = false;
            float as_n;
            ushort4 xv_n;
            if (more) {
                int en = e + g;
                v_n = en < e1;
                int j_n = ssrc[v_n ? en : e1 - 1];
                as_n = asrc[j_n];
                xv_n = *(const ushort4*)(xw2 + (size_t)j_n * 64 + f0);
            }
            float w = v_c ? __expf(lrelu(as_c + ad) - m) : 0.0f;
            s += w;
            acc[0] += w * bf2f(xv_c.x); acc[1] += w * bf2f(xv_c.y);
            acc[2] += w * bf2f(xv_c.z); acc[3] += w * bf2f(xv_c.w);
            if (!more) break;
            v_c = v_n; as_c = as_n; xv_c = xv_n;
        }
    }
    s += __shfl_xor(s, 16, 64);
    s += __shfl_xor(s, 32, 64);
    #pragma unroll
    for (int i = 0; i < 4; ++i) {
        acc[i] += __shfl_xor(acc[i], 16, 64);
        acc[i] += __shfl_xor(acc[i], 32, 64);
    }
    float inv = 1.0f / (s + EPS_GAT);
    float val[4];
    float mx = -1e30f;
    #pragma unroll
    for (int i = 0; i < 4; ++i) {
        val[i] = acc[i] * inv + b2[f0 + i];
        mx = fmaxf(mx, val[i]);
    }
    #pragma unroll
    for (int off = 8; off > 0; off >>= 1) mx = fmaxf(mx, __shfl_xor(mx, off, 64));
    float sm = 0.f;
    #pragma unroll
    for (int i = 0; i < 4; ++i) sm += __expf(val[i] - mx);
    #pragma unroll
    for (int off = 8; off > 0; off >>= 1) sm += __shfl_xor(sm, off, 64);
    float lse = mx + logf(sm);
    if (g == 0) {
        float4 o = make_float4(val[0] - lse, val[1] - lse, val[2] - lse, val[3] - lse);
        *(float4*)(out + (size_t)wid * 64 + f0) = o;
    }
}

// ------------------------------- launcher ----------------------------------
static inline int cdiv(int a, int b) { return (a + b - 1) / b; }

extern "C" void kernel_launch(void* const* d_in, const int* in_sizes, int n_in,
                              void* d_out, int out_size, void* d_ws, size_t ws_size,
                              hipStream_t stream) {
    const float* x   = (const float*)d_in[0];
    const void*  eix = d_in[1];
    const float* W1  = (const float*)d_in[2];
    const float* as1 = (const float*)d_in[3];
    const float* ad1 = (const float*)d_in[4];
    const float* b1  = (const float*)d_in[5];
    const float* W2  = (const float*)d_in[6];
    const float* as2 = (const float*)d_in[7];
    const float* ad2 = (const float*)d_in[8];
    const float* b2  = (const float*)d_in[9];
    float* out = (float*)d_out;

    const int N = in_sizes[0] / 512;
    const int E = in_sizes[1] / 2;
    const int NB = cdiv(N, 256);
    const int NB1 = cdiv(N * 8, 256);
    const int NB2 = cdiv(N, 256);
    (void)n_in; (void)out_size; (void)ws_size;

    char* base = (char*)d_ws;
    size_t o = 0;
    auto alloc = [&](size_t bytes) -> char* {
        o = (o + 255) & ~(size_t)255;
        char* p = base + o;
        o += bytes;
        return p;
    };
    unsigned short* xw1b  = (unsigned short*)alloc((size_t)N * 256 * 2);
    unsigned short* hbf   = (unsigned short*)alloc((size_t)N * 256 * 2);
    unsigned short* xw2b  = (unsigned short*)alloc((size_t)N * 64 * 2);
    float*          asrc1 = (float*)alloc((size_t)N * 8 * 4);
    float*          adst1 = (float*)alloc((size_t)N * 8 * 4);
    float*          asrc2 = (float*)alloc((size_t)N * 4);
    float*          adst2 = (float*)alloc((size_t)N * 4);
    float*          pmax1 = (float*)alloc((size_t)NB1 * 8 * 4);
    float*          pmax2 = (float*)alloc((size_t)NB2 * 4);
    float*          M1    = (float*)alloc(8 * 4);
    float*          M2    = (float*)alloc(4);
    unsigned short* w1t   = (unsigned short*)alloc(512 * 256 * 2);
    unsigned short* w2t   = (unsigned short*)alloc(256 * 64 * 2);
    int*            counts= (int*)alloc((size_t)N * 4);
    int*            cursor= (int*)alloc((size_t)N * 4);
    int*            rowp  = (int*)alloc((size_t)(N + 1) * 4);
    int*            bsum  = (int*)alloc(256 * 4);
    int*            boff  = (int*)alloc(256 * 4);
    int*            esrc  = (int*)alloc((size_t)E * 4);
    int*            edst  = (int*)alloc((size_t)E * 4);
    int*            ssrc  = (int*)alloc((size_t)E * 4);
    unsigned*       sent  = (unsigned*)alloc(256);

    hipMemsetAsync(sent, 0, 4, stream);
    hipMemsetAsync(counts, 0, (size_t)N * 4, stream);

    // edge normalization + CSR
    k_flag<<<1, 256, 0, stream>>>((const unsigned*)eix, sent, E);
    k_convert<<<cdiv(2 * E, 256), 256, 0, stream>>>(eix, sent, esrc, edst, counts, E);
    k_scan1<<<NB, 256, 0, stream>>>(counts, rowp, bsum, N);
    k_scan2<<<1, 256, 0, stream>>>(bsum, boff, rowp + N, NB);
    k_scan3<<<NB, 256, 0, stream>>>(rowp, cursor, boff, N);
    k_fill<<<cdiv(E, 256), 256, 0, stream>>>(esrc, edst, cursor, ssrc, E);

    // weights -> bf16 transposed
    k_prep_w<<<cdiv(512 * 256 + 256 * 64, 256), 256, 0, stream>>>(W1, W2, w1t, w2t);

    // layer 1
    k_gemm<128, 256, 512, true, true><<<cdiv(N, 128), 512, 0, stream>>>(x, w1t, xw1b, N, 512);
    k_alpha<<<NB1, 256, 0, stream>>>(xw1b, as1, ad1, asrc1, adst1, pmax1, N * 8, 8, 32);
    k_maxred<<<1, 256, 0, stream>>>(pmax1, NB1, 8, M1);
    k_agg_l1<<<cdiv(N * 64, 256), 256, 0, stream>>>(xw1b, asrc1, adst1, M1, b1,
                                                    rowp, ssrc, hbf, N);
    // layer 2
    k_gemm<256, 64, 256, false, true><<<cdiv(N, 256), 256, 0, stream>>>(hbf, w2t, xw2b, N, 256);
    k_alpha<<<NB2, 256, 0, stream>>>(xw2b, as2, ad2, asrc2, adst2, pmax2, N, 1, 64);
    k_maxred<<<1, 256, 0, stream>>>(pmax2, NB2, 1, M2);
    k_agg_l2<<<cdiv(N * 64, 256), 256, 0, stream>>>(xw2b, asrc2, adst2, M2, b2,
                                                    rowp, ssrc, out, N);
}

// Round 5
// 438.456 us; speedup vs baseline: 1.8942x; 1.0242x over previous
//
#include <hip/hip_runtime.h>
#include <hip/hip_bf16.h>

// ---------------------------------------------------------------------------
// GAT (2-layer, PyG-style) on MI355X.
// R5: agg_l1 -> 4 edges/wave (16 lanes x 32B) + 2-deep software pipeline;
//     agg_l2 2-deep pipeline; k_maxred removed (atomicMax on encoded floats
//     fused into k_alpha); GEMM1 A-staging uses packed v_cvt_pk_bf16_f32.
//     Global-per-head-max softmax (rescale-free). xw1/xw2 bf16.
// ---------------------------------------------------------------------------

typedef __attribute__((ext_vector_type(8)))  __bf16          bf16x8;
typedef __attribute__((ext_vector_type(8)))  unsigned short  ushort8;
typedef __attribute__((ext_vector_type(16))) float           f32x16;

#define NEG_SLOPE 0.2f
#define EPS_GAT 1e-16f

static __device__ __forceinline__ float lrelu(float x) {
    return x > 0.0f ? x : NEG_SLOPE * x;
}
static __device__ __forceinline__ unsigned short f2bf(float f) {
    unsigned u = __float_as_uint(f);
    return (unsigned short)((u + 0x7fffu + ((u >> 16) & 1u)) >> 16);
}
static __device__ __forceinline__ float bf2f(unsigned short v) {
    return __uint_as_float(((unsigned)v) << 16);
}
// ordered-uint encoding for float atomicMax; enc is monotone, enc(x)>0 for all
// finite x, so memset-0 init acts as -inf.
static __device__ __forceinline__ unsigned encf(float x) {
    unsigned u = __float_as_uint(x);
    return (u >> 31) ? ~u : (u | 0x80000000u);
}
static __device__ __forceinline__ float decf(unsigned e) {
    unsigned u = (e >> 31) ? (e & 0x7fffffffu) : ~e;
    return __uint_as_float(u);
}

// --------------------------- edge normalization ----------------------------
__global__ void k_flag(const unsigned* __restrict__ p, unsigned* sentinel, int E) {
    __shared__ int anynz;
    if (threadIdx.x == 0) anynz = 0;
    __syncthreads();
    int i = threadIdx.x;
    unsigned w = (i < E) ? p[2 * i + 1] : 0u;
    if (w != 0u) atomicOr(&anynz, 1);
    __syncthreads();
    if (threadIdx.x == 0 && anynz) *sentinel = 1u;   // 1 => int32 data
}

__global__ void k_convert(const void* __restrict__ p, const unsigned* __restrict__ sentinel,
                          int* __restrict__ esrc, int* __restrict__ edst,
                          int* __restrict__ counts, int E) {
    int i = blockIdx.x * 256 + threadIdx.x;
    if (i >= 2 * E) return;
    bool is64 = (*sentinel == 0u);
    int v = is64 ? (int)((const long long*)p)[i] : ((const int*)p)[i];
    if (i < E) {
        esrc[i] = v;
    } else {
        edst[i - E] = v;
        atomicAdd(&counts[v], 1);
    }
}

// ------------------------------- CSR build ---------------------------------
__global__ void k_scan1(const int* __restrict__ counts, int* __restrict__ rowp,
                        int* __restrict__ bsum, int N) {
    __shared__ int s[256];
    int t = threadIdx.x, i = blockIdx.x * 256 + t;
    int v = (i < N) ? counts[i] : 0;
    s[t] = v;
    __syncthreads();
    for (int off = 1; off < 256; off <<= 1) {
        int u = (t >= off) ? s[t - off] : 0;
        __syncthreads();
        s[t] += u;
        __syncthreads();
    }
    if (i < N) rowp[i] = s[t] - v;
    if (t == 255) bsum[blockIdx.x] = s[255];
}

__global__ void k_scan2(const int* __restrict__ bsum, int* __restrict__ boff,
                        int* __restrict__ rowp_last, int NB) {
    __shared__ int s[256];
    int t = threadIdx.x;
    int v = (t < NB) ? bsum[t] : 0;
    s[t] = v;
    __syncthreads();
    for (int off = 1; off < 256; off <<= 1) {
        int u = (t >= off) ? s[t - off] : 0;
        __syncthreads();
        s[t] += u;
        __syncthreads();
    }
    if (t < NB) boff[t] = s[t] - v;
    if (t == 255) *rowp_last = s[255];
}

__global__ void k_scan3(int* __restrict__ rowp, int* __restrict__ cursor,
                        const int* __restrict__ boff, int N) {
    int i = blockIdx.x * 256 + threadIdx.x;
    if (i < N) {
        int r = rowp[i] + boff[blockIdx.x];
        rowp[i] = r;
        cursor[i] = r;
    }
}

__global__ void k_fill(const int* __restrict__ esrc, const int* __restrict__ edst,
                       int* __restrict__ cursor, int* __restrict__ sorted_src, int E) {
    int i = blockIdx.x * 256 + threadIdx.x;
    if (i >= E) return;
    int d = edst[i];
    int pos = atomicAdd(&cursor[d], 1);
    sorted_src[pos] = esrc[i];
}

// --------------------------- weight prep (bf16^T) --------------------------
__global__ void k_prep_w(const float* __restrict__ W1, const float* __restrict__ W2,
                         unsigned short* __restrict__ w1t, unsigned short* __restrict__ w2t) {
    int t = blockIdx.x * 256 + threadIdx.x;
    if (t < 512 * 256) {
        int k = t >> 8, m = t & 255;
        w1t[m * 512 + k] = f2bf(W1[t]);
    } else {
        int u = t - 512 * 256;
        if (u < 256 * 64) {
            int k = u >> 6, m = u & 63;
            w2t[m * 256 + k] = f2bf(W2[u]);
        }
    }
}

// ------------------------------- bf16 GEMM ---------------------------------
template <int BM, int BN, int NT, bool AF32, bool OUTBF>
__global__ __launch_bounds__(NT) void k_gemm(const void* __restrict__ Ain,
                                             const unsigned short* __restrict__ Bt,
                                             void* __restrict__ Cout, int Nrows, int K) {
    constexpr int LD = 40;
    __shared__ __align__(16) unsigned short As[BM * LD];
    __shared__ __align__(16) unsigned short Bs[BN * LD];
    const int tid = threadIdx.x;
    const int blockRow = blockIdx.x * BM;
    const int wave = tid >> 6, lane = tid & 63;
    constexpr int WR = BM / 64;
    const int wr = wave % WR, wc = wave / WR;
    const int m = lane & 31;
    const int ksel = (lane >> 5) * 8;

    f32x16 acc00{}, acc01{}, acc10{}, acc11{};

    for (int kt = 0; kt < K; kt += 32) {
        if constexpr (AF32) {
            const float* A = (const float*)Ain;
            for (int idx = tid; idx < BM * 4; idx += NT) {
                int r = idx >> 2, kc = (idx & 3) * 8;
                int grow = blockRow + r;
                union { ushort8 u; __hip_bfloat162 h[4]; } cv;
                if (grow < Nrows) {
                    const float* ap = A + (size_t)grow * K + kt + kc;
                    float4 x0 = *(const float4*)ap;
                    float4 x1 = *(const float4*)(ap + 4);
                    cv.h[0] = __float22bfloat162_rn(make_float2(x0.x, x0.y));
                    cv.h[1] = __float22bfloat162_rn(make_float2(x0.z, x0.w));
                    cv.h[2] = __float22bfloat162_rn(make_float2(x1.x, x1.y));
                    cv.h[3] = __float22bfloat162_rn(make_float2(x1.z, x1.w));
                } else {
                    cv.u = ushort8{};
                }
                *(ushort8*)&As[r * LD + kc] = cv.u;
            }
        } else {
            const unsigned short* A = (const unsigned short*)Ain;
            for (int idx = tid; idx < BM * 4; idx += NT) {
                int r = idx >> 2, kc = (idx & 3) * 8;
                int grow = blockRow + r;
                ushort8 o{};
                if (grow < Nrows) o = *(const ushort8*)(A + (size_t)grow * K + kt + kc);
                *(ushort8*)&As[r * LD + kc] = o;
            }
        }
        for (int idx = tid; idx < BN * 4; idx += NT) {
            int r = idx >> 2, kc = (idx & 3) * 8;
            *(ushort8*)&Bs[r * LD + kc] = *(const ushort8*)(Bt + (size_t)r * K + kt + kc);
        }
        __syncthreads();

        #pragma unroll
        for (int kk = 0; kk < 32; kk += 16) {
            bf16x8 a0 = *(const bf16x8*)&As[(wr * 64 +      m) * LD + kk + ksel];
            bf16x8 a1 = *(const bf16x8*)&As[(wr * 64 + 32 + m) * LD + kk + ksel];
            bf16x8 b0 = *(const bf16x8*)&Bs[(wc * 64 +      m) * LD + kk + ksel];
            bf16x8 b1 = *(const bf16x8*)&Bs[(wc * 64 + 32 + m) * LD + kk + ksel];
            acc00 = __builtin_amdgcn_mfma_f32_32x32x16_bf16(a0, b0, acc00, 0, 0, 0);
            acc01 = __builtin_amdgcn_mfma_f32_32x32x16_bf16(a0, b1, acc01, 0, 0, 0);
            acc10 = __builtin_amdgcn_mfma_f32_32x32x16_bf16(a1, b0, acc10, 0, 0, 0);
            acc11 = __builtin_amdgcn_mfma_f32_32x32x16_bf16(a1, b1, acc11, 0, 0, 0);
        }
        __syncthreads();
    }

    const int dcol = wc * 64 + (lane & 31);
    const int dquad = 4 * (lane >> 5);
    auto store_tile = [&](const f32x16& a, int rt, int ct) {
        #pragma unroll
        for (int r = 0; r < 16; ++r) {
            int row = blockRow + wr * 64 + rt * 32 + (r & 3) + 8 * (r >> 2) + dquad;
            if (row < Nrows) {
                size_t off = (size_t)row * BN + dcol + ct * 32;
                if constexpr (OUTBF) ((unsigned short*)Cout)[off] = f2bf(a[r]);
                else                 ((float*)Cout)[off] = a[r];
            }
        }
    };
    store_tile(acc00, 0, 0); store_tile(acc01, 0, 1);
    store_tile(acc10, 1, 0); store_tile(acc11, 1, 1);
}

// ----------- attention logits + global head max (atomicMax enc) ------------
__global__ void k_alpha(const unsigned short* __restrict__ xw, const float* __restrict__ a_s,
                        const float* __restrict__ a_d, float* __restrict__ os,
                        float* __restrict__ od, unsigned* __restrict__ Menc,
                        int NH, int H, int C) {
    __shared__ float red[256];
    int t = blockIdx.x * 256 + threadIdx.x;
    float s = -1e30f, d = 0.f;
    if (t < NH) {
        int n = t / H, h = t - n * H;
        const unsigned short* row = xw + (size_t)n * H * C + h * C;
        s = 0.f;
        for (int c = 0; c < C; c += 8) {
            ushort8 v = *(const ushort8*)(row + c);
            #pragma unroll
            for (int q = 0; q < 8; ++q) {
                float f = bf2f(v[q]);
                s += f * a_s[h * C + c + q];
                d += f * a_d[h * C + c + q];
            }
        }
        os[t] = s; od[t] = d;
    }
    red[threadIdx.x] = s;
    __syncthreads();
    for (int off = 128; off >= H; off >>= 1) {
        if (threadIdx.x < off) red[threadIdx.x] = fmaxf(red[threadIdx.x], red[threadIdx.x + off]);
        __syncthreads();
    }
    if ((int)threadIdx.x < H) atomicMax(&Menc[threadIdx.x], encf(red[threadIdx.x]));
}

// ------ layer 1: 4-edges-per-wave rescale-free agg, 2-deep pipeline --------
// g = lane>>4 picks edge of quad; q = lane&15 holds features [q*16, q*16+16)
__global__ __launch_bounds__(256) void k_agg_l1(
        const unsigned short* __restrict__ xw1, const float* __restrict__ asrc,
        const float* __restrict__ adst, const unsigned* __restrict__ Menc,
        const float* __restrict__ b1, const int* __restrict__ rp,
        const int* __restrict__ ssrc, unsigned short* __restrict__ hbf, int N) {
    int wid = (blockIdx.x * 256 + threadIdx.x) >> 6;
    if (wid >= N) return;
    int lane = threadIdx.x & 63;
    int g  = lane >> 4;
    int q  = lane & 15;
    int f0 = q * 16;
    int h  = q >> 1;
    int ih = wid * 8 + h;
    float ad = adst[ih];
    float m  = lrelu(decf(Menc[h]) + ad);   // >= all edge logits (lrelu monotone)
    float acc[16];
    float s;
    {   // self loop counted on group 0 only
        float w = (g == 0) ? __expf(lrelu(asrc[ih] + ad) - m) : 0.0f;
        const unsigned short* rowp_ = xw1 + (size_t)wid * 256 + f0;
        ushort8 lo = *(const ushort8*)rowp_;
        ushort8 hi = *(const ushort8*)(rowp_ + 8);
        s = w;
        #pragma unroll
        for (int i = 0; i < 8; ++i) { acc[i] = w * bf2f(lo[i]); acc[8 + i] = w * bf2f(hi[i]); }
    }
    int e0 = rp[wid], e1 = rp[wid + 1];
    if (e0 < e1) {
        auto loadSlot = [&](int ebase, float& as, ushort8& lo, ushort8& hi, bool& val) {
            int ei = ebase + g;
            val = ei < e1;
            int j = ssrc[val ? ei : e1 - 1];
            as = asrc[j * 8 + h];
            const unsigned short* rp_ = xw1 + (size_t)j * 256 + f0;
            lo = *(const ushort8*)rp_;
            hi = *(const ushort8*)(rp_ + 8);
        };
        float asA; ushort8 loA, hiA; bool vA;
        loadSlot(e0, asA, loA, hiA, vA);
        float asB = 0.f; ushort8 loB{}, hiB{}; bool vB = false;
        bool moreB = e0 + 4 < e1;
        if (moreB) loadSlot(e0 + 4, asB, loB, hiB, vB);
        for (int e = e0;;) {
            float asC = 0.f; ushort8 loC{}, hiC{}; bool vC = false;
            bool moreC = e + 8 < e1;
            if (moreC) loadSlot(e + 8, asC, loC, hiC, vC);
            float w = vA ? __expf(lrelu(asA + ad) - m) : 0.0f;
            s += w;
            #pragma unroll
            for (int i = 0; i < 8; ++i) {
                acc[i]     += w * bf2f(loA[i]);
                acc[8 + i] += w * bf2f(hiA[i]);
            }
            if (!moreB) break;
            asA = asB; loA = loB; hiA = hiB; vA = vB;
            asB = asC; loB = loC; hiB = hiC; vB = vC;
            moreB = moreC;
            e += 4;
        }
    }
    // combine the 4 edge-groups
    s += __shfl_xor(s, 16, 64);
    s += __shfl_xor(s, 32, 64);
    #pragma unroll
    for (int i = 0; i < 16; ++i) {
        acc[i] += __shfl_xor(acc[i], 16, 64);
        acc[i] += __shfl_xor(acc[i], 32, 64);
    }
    float inv = 1.0f / (s + EPS_GAT);
    // group g writes features [f0 + g*4, f0 + g*4 + 4)
    int fw = f0 + g * 4;
    ushort4 o;
    #pragma unroll
    for (int i = 0; i < 4; ++i) {
        float v = acc[g * 4 + i] * inv + b1[fw + i];
        v = v > 0.f ? v : expm1f(v);
        ((unsigned short*)&o)[i] = f2bf(v);
    }
    *(ushort4*)(hbf + (size_t)wid * 256 + fw) = o;
}

// ---- layer 2: 4-edges-per-wave agg + log_softmax, 2-deep pipeline ---------
// g = lane>>4 picks edge of quad; q = lane&15 holds classes [q*4, q*4+4)
__global__ __launch_bounds__(256) void k_agg_l2(
        const unsigned short* __restrict__ xw2, const float* __restrict__ asrc,
        const float* __restrict__ adst, const unsigned* __restrict__ Menc,
        const float* __restrict__ b2, const int* __restrict__ rp,
        const int* __restrict__ ssrc, float* __restrict__ out, int N) {
    int wid = (blockIdx.x * 256 + threadIdx.x) >> 6;
    if (wid >= N) return;
    int lane = threadIdx.x & 63;
    int g  = lane >> 4;
    int q  = lane & 15;
    int f0 = q * 4;
    float ad = adst[wid];
    float m = lrelu(decf(Menc[0]) + ad);
    float acc[4];
    float s;
    {   // self loop counted on group 0 only
        float w = (g == 0) ? __expf(lrelu(asrc[wid] + ad) - m) : 0.0f;
        ushort4 xv = *(const ushort4*)(xw2 + (size_t)wid * 64 + f0);
        s = w;
        acc[0] = w * bf2f(xv.x); acc[1] = w * bf2f(xv.y);
        acc[2] = w * bf2f(xv.z); acc[3] = w * bf2f(xv.w);
    }
    int e0 = rp[wid], e1 = rp[wid + 1];
    if (e0 < e1) {
        auto loadSlot = [&](int ebase, float& as, ushort4& xv, bool& val) {
            int ei = ebase + g;
            val = ei < e1;
            int j = ssrc[val ? ei : e1 - 1];
            as = asrc[j];
            xv = *(const ushort4*)(xw2 + (size_t)j * 64 + f0);
        };
        float asA; ushort4 xvA; bool vA;
        loadSlot(e0, asA, xvA, vA);
        float asB = 0.f; ushort4 xvB = {0, 0, 0, 0}; bool vB = false;
        bool moreB = e0 + 4 < e1;
        if (moreB) loadSlot(e0 + 4, asB, xvB, vB);
        for (int e = e0;;) {
            float asC = 0.f; ushort4 xvC = {0, 0, 0, 0}; bool vC = false;
            bool moreC = e + 8 < e1;
            if (moreC) loadSlot(e + 8, asC, xvC, vC);
            float w = vA ? __expf(lrelu(asA + ad) - m) : 0.0f;
            s += w;
            acc[0] += w * bf2f(xvA.x); acc[1] += w * bf2f(xvA.y);
            acc[2] += w * bf2f(xvA.z); acc[3] += w * bf2f(xvA.w);
            if (!moreB) break;
            asA = asB; xvA = xvB; vA = vB;
            asB = asC; xvB = xvC; vB = vC;
            moreB = moreC;
            e += 4;
        }
    }
    s += __shfl_xor(s, 16, 64);
    s += __shfl_xor(s, 32, 64);
    #pragma unroll
    for (int i = 0; i < 4; ++i) {
        acc[i] += __shfl_xor(acc[i], 16, 64);
        acc[i] += __shfl_xor(acc[i], 32, 64);
    }
    float inv = 1.0f / (s + EPS_GAT);
    float val[4];
    float mx = -1e30f;
    #pragma unroll
    for (int i = 0; i < 4; ++i) {
        val[i] = acc[i] * inv + b2[f0 + i];
        mx = fmaxf(mx, val[i]);
    }
    #pragma unroll
    for (int off = 8; off > 0; off >>= 1) mx = fmaxf(mx, __shfl_xor(mx, off, 64));
    float sm = 0.f;
    #pragma unroll
    for (int i = 0; i < 4; ++i) sm += __expf(val[i] - mx);
    #pragma unroll
    for (int off = 8; off > 0; off >>= 1) sm += __shfl_xor(sm, off, 64);
    float lse = mx + logf(sm);
    if (g == 0) {
        float4 o = make_float4(val[0] - lse, val[1] - lse, val[2] - lse, val[3] - lse);
        *(float4*)(out + (size_t)wid * 64 + f0) = o;
    }
}

// ------------------------------- launcher ----------------------------------
static inline int cdiv(int a, int b) { return (a + b - 1) / b; }

extern "C" void kernel_launch(void* const* d_in, const int* in_sizes, int n_in,
                              void* d_out, int out_size, void* d_ws, size_t ws_size,
                              hipStream_t stream) {
    const float* x   = (const float*)d_in[0];
    const void*  eix = d_in[1];
    const float* W1  = (const float*)d_in[2];
    const float* as1 = (const float*)d_in[3];
    const float* ad1 = (const float*)d_in[4];
    const float* b1  = (const float*)d_in[5];
    const float* W2  = (const float*)d_in[6];
    const float* as2 = (const float*)d_in[7];
    const float* ad2 = (const float*)d_in[8];
    const float* b2  = (const float*)d_in[9];
    float* out = (float*)d_out;

    const int N = in_sizes[0] / 512;
    const int E = in_sizes[1] / 2;
    const int NB = cdiv(N, 256);
    const int NB1 = cdiv(N * 8, 256);
    const int NB2 = cdiv(N, 256);
    (void)n_in; (void)out_size; (void)ws_size;

    char* base = (char*)d_ws;
    size_t o = 0;
    auto alloc = [&](size_t bytes) -> char* {
        o = (o + 255) & ~(size_t)255;
        char* p = base + o;
        o += bytes;
        return p;
    };
    unsigned short* xw1b  = (unsigned short*)alloc((size_t)N * 256 * 2);
    unsigned short* hbf   = (unsigned short*)alloc((size_t)N * 256 * 2);
    unsigned short* xw2b  = (unsigned short*)alloc((size_t)N * 64 * 2);
    float*          asrc1 = (float*)alloc((size_t)N * 8 * 4);
    float*          adst1 = (float*)alloc((size_t)N * 8 * 4);
    float*          asrc2 = (float*)alloc((size_t)N * 4);
    float*          adst2 = (float*)alloc((size_t)N * 4);
    unsigned*       Menc  = (unsigned*)alloc(16 * 4);   // [0..7]=L1 heads, [8]=L2
    unsigned short* w1t   = (unsigned short*)alloc(512 * 256 * 2);
    unsigned short* w2t   = (unsigned short*)alloc(256 * 64 * 2);
    int*            counts= (int*)alloc((size_t)N * 4);
    int*            cursor= (int*)alloc((size_t)N * 4);
    int*            rowp  = (int*)alloc((size_t)(N + 1) * 4);
    int*            bsum  = (int*)alloc(256 * 4);
    int*            boff  = (int*)alloc(256 * 4);
    int*            esrc  = (int*)alloc((size_t)E * 4);
    int*            edst  = (int*)alloc((size_t)E * 4);
    int*            ssrc  = (int*)alloc((size_t)E * 4);
    unsigned*       sent  = (unsigned*)alloc(256);

    hipMemsetAsync(sent, 0, 4, stream);
    hipMemsetAsync(Menc, 0, 16 * 4, stream);            // enc-space -inf
    hipMemsetAsync(counts, 0, (size_t)N * 4, stream);

    // edge normalization + CSR
    k_flag<<<1, 256, 0, stream>>>((const unsigned*)eix, sent, E);
    k_convert<<<cdiv(2 * E, 256), 256, 0, stream>>>(eix, sent, esrc, edst, counts, E);
    k_scan1<<<NB, 256, 0, stream>>>(counts, rowp, bsum, N);
    k_scan2<<<1, 256, 0, stream>>>(bsum, boff, rowp + N, NB);
    k_scan3<<<NB, 256, 0, stream>>>(rowp, cursor, boff, N);
    k_fill<<<cdiv(E, 256), 256, 0, stream>>>(esrc, edst, cursor, ssrc, E);

    // weights -> bf16 transposed
    k_prep_w<<<cdiv(512 * 256 + 256 * 64, 256), 256, 0, stream>>>(W1, W2, w1t, w2t);

    // layer 1
    k_gemm<128, 256, 512, true, true><<<cdiv(N, 128), 512, 0, stream>>>(x, w1t, xw1b, N, 512);
    k_alpha<<<NB1, 256, 0, stream>>>(xw1b, as1, ad1, asrc1, adst1, Menc, N * 8, 8, 32);
    k_agg_l1<<<cdiv(N * 64, 256), 256, 0, stream>>>(xw1b, asrc1, adst1, Menc, b1,
                                                    rowp, ssrc, hbf, N);
    // layer 2
    k_gemm<256, 64, 256, false, true><<<cdiv(N, 256), 256, 0, stream>>>(hbf, w2t, xw2b, N, 256);
    k_alpha<<<NB2, 256, 0, stream>>>(xw2b, as2, ad2, asrc2, adst2, Menc + 8, N, 1, 64);
    k_agg_l2<<<cdiv(N * 64, 256), 256, 0, stream>>>(xw2b, asrc2, adst2, Menc + 8, b2,
                                                    rowp, ssrc, out, N);
}